// Round 1
// baseline (1649.687 us; speedup 1.0000x reference)
//
#include <hip/hip_runtime.h>
#include <stdint.h>
#include <stddef.h>

constexpr int IMH = 192;
constexpr int IMW = 192;
constexpr int HW  = 36864;   // 192*192
constexpr int BB  = 2;
constexpr int CC  = 64;
constexpr int CHF = 32;      // half channels (sorted part)
constexpr int C5  = 320;     // 5*CC
constexpr int NQ  = 9216;    // HW/4
constexpr int CROWS = 64;    // fuse-pipeline chunk rows
constexpr int CHWN  = CROWS * IMW;  // 12288 cols per chunk
constexpr int NCHUNK = 32;   // attn_qk n-chunks per z
constexpr int CHN = HW / 4 / NCHUNK;  // 288 n per chunk
constexpr int NSEG = 16;     // radix segments per row
constexpr int SEGN = HW / NSEG;      // 2304 elements per segment (= 9 * 256)
constexpr int NBIN = 2048;   // 11-bit radix

// ---------- float <-> monotone uint32 (order-preserving, invertible) ----------
static __device__ __forceinline__ uint32_t f2s(float f) {
    uint32_t u = __float_as_uint(f);
    return (u & 0x80000000u) ? ~u : (u | 0x80000000u);
}
static __device__ __forceinline__ float s2f(uint32_t s) {
    uint32_t u = (s & 0x80000000u) ? (s & 0x7FFFFFFFu) : ~s;
    return __uint_as_float(u);
}

// ---------- bitonic sort of 256 u64 keys in LDS (128 threads) ----------
static __device__ void bitonic256(uint64_t* keys, int tid) {
    for (unsigned k = 2; k <= 256; k <<= 1) {
        for (unsigned j = k >> 1; j; j >>= 1) {
            __syncthreads();
            unsigned i = ((tid & ~(j - 1)) << 1) | (tid & (j - 1));
            unsigned p = i | j;
            bool up = ((i & k) == 0);
            uint64_t a = keys[i], b = keys[p];
            if ((a > b) == up) { keys[i] = b; keys[p] = a; }
        }
    }
    __syncthreads();
}

// ---------- K0: copy unsorted half channels into A ----------
__global__ void k_copy_back(const float* __restrict__ x, float* __restrict__ A) {
    int i = blockIdx.x * 256 + threadIdx.x;        // over BB*CHF*HW
    int b = i / (CHF * HW);
    int r = i % (CHF * HW);
    size_t o = ((size_t)(b * CC) + CHF) * HW + r;
    A[o] = x[o];
}

// ---------- K1: stable sort along H (per b,c,w column), write A + idx_h ----------
__global__ __launch_bounds__(128) void k_sort_h(const float* __restrict__ x, float* __restrict__ A,
                                                int* __restrict__ idx_h) {
    __shared__ uint64_t keys[256];
    int tid = threadIdx.x;
    int blk = blockIdx.x;
    int w = blk % IMW;
    int c = (blk / IMW) % CHF;
    int b = blk / (IMW * CHF);
    const float* col = x + ((size_t)(b * CC) + c) * HW + w;
    for (int i = tid; i < 256; i += 128)
        keys[i] = (i < IMH) ? ((((uint64_t)f2s(col[(size_t)i * IMW])) << 32) | (uint32_t)i) : ~0ull;
    bitonic256(keys, tid);
    float* ocol = A + ((size_t)(b * CC) + c) * HW + w;
    int* icol = idx_h + ((size_t)(b * CHF) + c) * HW + w;
    for (int i = tid; i < IMH; i += 128) {
        uint64_t k = keys[i];
        ocol[(size_t)i * IMW] = s2f((uint32_t)(k >> 32));
        icol[(size_t)i * IMW] = (int)(k & 0xFFFFFFFFull);
    }
}

// ---------- K2: stable sort along W (per b,c,h row), in-place on A, write idx_w ----------
__global__ __launch_bounds__(128) void k_sort_w(float* __restrict__ A, int* __restrict__ idx_w) {
    __shared__ uint64_t keys[256];
    int tid = threadIdx.x;
    int blk = blockIdx.x;
    int h = blk % IMH;
    int c = (blk / IMH) % CHF;
    int b = blk / (IMH * CHF);
    float* row = A + ((size_t)(b * CC) + c) * HW + (size_t)h * IMW;
    for (int i = tid; i < 256; i += 128)
        keys[i] = (i < IMW) ? ((((uint64_t)f2s(row[i])) << 32) | (uint32_t)i) : ~0ull;
    bitonic256(keys, tid);
    int* irow = idx_w + ((size_t)(b * CHF) + c) * HW + (size_t)h * IMW;
    for (int i = tid; i < IMW; i += 128) {
        uint64_t k = keys[i];
        row[i] = s2f((uint32_t)(k >> 32));
        irow[i] = (int)(k & 0xFFFFFFFFull);
    }
}

// ---------- K3: q = W_qkv(320x64) * A(64xHW) per batch ----------
__global__ __launch_bounds__(256) void k_gemm_q(const float* __restrict__ wq, const float* __restrict__ A,
                                                float* __restrict__ q) {
    __shared__ float Wt[64][68];
    __shared__ float Xt[64][68];
    int tid = threadIdx.x;
    int n0 = blockIdx.x * 64, m0 = blockIdx.y * 64, b = blockIdx.z;
    for (int l = 0; l < 16; ++l) {
        int idx = l * 256 + tid;
        int cc = idx & 63, m = idx >> 6;
        Wt[cc][m] = wq[(size_t)(m0 + m) * 64 + cc];
    }
    for (int l = 0; l < 16; ++l) {
        int idx = l * 256 + tid;
        int n = idx & 63, cc = idx >> 6;
        Xt[cc][n] = A[((size_t)(b * CC) + cc) * HW + n0 + n];
    }
    __syncthreads();
    int ty = tid >> 4, tx = tid & 15;
    float acc[4][4] = {};
    for (int cc = 0; cc < 64; ++cc) {
        float4 av = *(const float4*)&Wt[cc][ty * 4];
        float4 bv = *(const float4*)&Xt[cc][tx * 4];
        float aa[4] = {av.x, av.y, av.z, av.w};
        float bb[4] = {bv.x, bv.y, bv.z, bv.w};
        #pragma unroll
        for (int i = 0; i < 4; ++i)
            #pragma unroll
            for (int j = 0; j < 4; ++j)
                acc[i][j] = fmaf(aa[i], bb[j], acc[i][j]);
    }
    for (int i = 0; i < 4; ++i) {
        float4 o;
        o.x = acc[i][0]; o.y = acc[i][1]; o.z = acc[i][2]; o.w = acc[i][3];
        *(float4*)&q[((size_t)(b * C5) + m0 + ty * 4 + i) * HW + n0 + tx * 4] = o;
    }
}

// ---------- K4: depthwise conv KSxKS (zero pad) for a 64-row chunk starting at r0 ----------
template <int KS>
__global__ __launch_bounds__(256) void k_dwconv(const float* __restrict__ q, const float* __restrict__ wd,
                                                float* __restrict__ slice, int r0) {
    constexpr int PAD = KS / 2;
    constexpr int EXT = 32 + 2 * PAD;
    __shared__ float tile[EXT][EXT];
    int tid = threadIdx.x;
    int b = blockIdx.z, c = blockIdx.y;
    int t = blockIdx.x;                  // 12 tiles: 2 tile-rows x 6 tile-cols
    int ty0 = r0 + (t / 6) * 32, tx0 = (t % 6) * 32;
    const float* src = q + ((size_t)(b * C5) + c) * HW;
    for (int i = tid; i < EXT * EXT; i += 256) {
        int iy = i / EXT, ix = i % EXT;
        int gy = ty0 + iy - PAD, gx = tx0 + ix - PAD;
        float v = 0.f;
        if (gy >= 0 && gy < IMH && gx >= 0 && gx < IMW) v = src[gy * IMW + gx];
        tile[iy][ix] = v;
    }
    __syncthreads();
    float wreg[KS * KS];
    #pragma unroll
    for (int i = 0; i < KS * KS; ++i) wreg[i] = wd[(size_t)c * KS * KS + i];
    float* dst = slice + ((size_t)(b * C5) + c) * CHWN;
    #pragma unroll
    for (int k = 0; k < 4; ++k) {
        int pix = k * 256 + tid;
        int py = pix >> 5, px = pix & 31;
        float acc = 0.f;
        #pragma unroll
        for (int ky = 0; ky < KS; ++ky)
            #pragma unroll
            for (int kx = 0; kx < KS; ++kx)
                acc = fmaf(tile[py + ky][px + kx], wreg[ky * KS + kx], acc);
        dst[(ty0 - r0 + py) * IMW + tx0 + px] = acc;
    }
}

// ---------- K5: qkv(chunk) (+)= W_fuse[:, g*320:(g+1)*320] * slice(chunk) ----------
// v3: 64x128 tile (960 blocks = 3.75/CU), 16x16 threads, 4m x 8n per thread,
// unit-stride LDS staging (conflict-free writes), LDS double-buffer, 1 barrier/iter.
__global__ __launch_bounds__(256) void k_gemm_fuse(const float* __restrict__ wf, const float* __restrict__ slice,
                                                   const float* __restrict__ bias, float* __restrict__ qkv,
                                                   int g, int r0) {
    __shared__ float Wt[2][16][68];
    __shared__ float Xt[2][16][132];
    int tid = threadIdx.x;
    int n0 = blockIdx.x * 128, m0 = blockIdx.y * 64, b = blockIdx.z;
    int gk = g * 320;
    int ty = tid >> 4, tx = tid & 15;                    // 16 x 16
    int wm = tid >> 2, wkq = (tid & 3) << 2;             // W stage: m = tid>>2, 4 consecutive kk
    int xkk = tid >> 5, xn = (tid & 31) * 4;             // X stage: kk = tid>>5 (+8), 4 consecutive n
    float acc[4][8] = {};

    const float* wsrc0 = &wf[(size_t)(m0 + wm) * 960 + gk + wkq];
    const float* xsrc0 = &slice[((size_t)(b * C5) + xkk) * CHWN + n0 + xn];

    float4 pw  = *(const float4*)wsrc0;
    float4 pxa = *(const float4*)xsrc0;
    float4 pxb = *(const float4*)(xsrc0 + (size_t)8 * CHWN);
    Wt[0][wkq + 0][wm] = pw.x;
    Wt[0][wkq + 1][wm] = pw.y;
    Wt[0][wkq + 2][wm] = pw.z;
    Wt[0][wkq + 3][wm] = pw.w;
    *(float4*)&Xt[0][xkk][xn]     = pxa;
    *(float4*)&Xt[0][xkk + 8][xn] = pxb;
    __syncthreads();

    int cur = 0;
    for (int k0 = 0; k0 < 320; k0 += 16) {
        bool more = (k0 + 16) < 320;
        if (more) {
            pw  = *(const float4*)(wsrc0 + (k0 + 16));
            const float* xsrc = xsrc0 + (size_t)(k0 + 16) * CHWN;
            pxa = *(const float4*)xsrc;
            pxb = *(const float4*)(xsrc + (size_t)8 * CHWN);
        }
        #pragma unroll
        for (int kk = 0; kk < 16; ++kk) {
            float4 av = *(const float4*)&Wt[cur][kk][ty * 4];
            float4 b0 = *(const float4*)&Xt[cur][kk][tx * 4];
            float4 b1 = *(const float4*)&Xt[cur][kk][64 + tx * 4];
            float aa[4] = {av.x, av.y, av.z, av.w};
            float bb[8] = {b0.x, b0.y, b0.z, b0.w, b1.x, b1.y, b1.z, b1.w};
            #pragma unroll
            for (int i = 0; i < 4; ++i)
                #pragma unroll
                for (int j = 0; j < 8; ++j)
                    acc[i][j] = fmaf(aa[i], bb[j], acc[i][j]);
        }
        if (more) {
            int nx = cur ^ 1;
            Wt[nx][wkq + 0][wm] = pw.x;
            Wt[nx][wkq + 1][wm] = pw.y;
            Wt[nx][wkq + 2][wm] = pw.z;
            Wt[nx][wkq + 3][wm] = pw.w;
            *(float4*)&Xt[nx][xkk][xn]     = pxa;
            *(float4*)&Xt[nx][xkk + 8][xn] = pxb;
            cur = nx;
            __syncthreads();
        }
    }

    #pragma unroll
    for (int i = 0; i < 4; ++i) {
        int m = m0 + ty * 4 + i;
        size_t base = ((size_t)(b * C5) + m) * HW + (size_t)r0 * IMW + n0;
        float* p0 = &qkv[base + tx * 4];
        float* p1 = &qkv[base + 64 + tx * 4];
        if (g == 0) {
            float bv = bias[m];
            float4 o0, o1;
            o0.x = acc[i][0] + bv; o0.y = acc[i][1] + bv; o0.z = acc[i][2] + bv; o0.w = acc[i][3] + bv;
            o1.x = acc[i][4] + bv; o1.y = acc[i][5] + bv; o1.z = acc[i][6] + bv; o1.w = acc[i][7] + bv;
            *(float4*)p0 = o0;
            *(float4*)p1 = o1;
        } else {
            float4 c0 = *(const float4*)p0;
            float4 c1 = *(const float4*)p1;
            c0.x += acc[i][0]; c0.y += acc[i][1]; c0.z += acc[i][2]; c0.w += acc[i][3];
            c1.x += acc[i][4]; c1.y += acc[i][5]; c1.z += acc[i][6]; c1.w += acc[i][7];
            *(float4*)p0 = c0;
            *(float4*)p1 = c1;
        }
    }
}

// ---------- K6a: build (value || index) u64 keys for v rows ----------
__global__ void k_build_keys(const float* __restrict__ qkv, uint64_t* __restrict__ keyA) {
    int j = blockIdx.x * 256 + threadIdx.x;
    int row = blockIdx.y;               // b*64+c
    int b = row >> 6, c = row & 63;
    float v = qkv[((size_t)(b * C5) + 256 + c) * HW + j];
    keyA[(size_t)row * HW + j] = (((uint64_t)f2s(v)) << 32) | (uint32_t)j;
}

// ---------- K6b-1: per-(row,seg) 11-bit digit histogram ----------
__global__ __launch_bounds__(256) void k_rcount(const uint64_t* __restrict__ in, uint32_t* __restrict__ cntG,
                                                int shift) {
    __shared__ uint32_t hist[NBIN];
    int t = threadIdx.x;
    int seg = blockIdx.x, row = blockIdx.y;
    #pragma unroll
    for (int k = 0; k < NBIN / 256; ++k) hist[k * 256 + t] = 0;
    __syncthreads();
    const uint64_t* src = in + (size_t)row * HW + (size_t)seg * SEGN;
    #pragma unroll
    for (int i = 0; i < SEGN / 256; ++i) {
        unsigned d = (unsigned)(src[i * 256 + t] >> shift) & (NBIN - 1);
        atomicAdd(&hist[d], 1u);
    }
    __syncthreads();
    uint32_t* dstc = cntG + ((size_t)row * NSEG + seg) * NBIN;
    #pragma unroll
    for (int k = 0; k < NBIN / 256; ++k) dstc[k * 256 + t] = hist[k * 256 + t];
}

// ---------- K6b-2: per-row two-level scan -> absolute dest base per (seg,digit) ----------
__global__ __launch_bounds__(256) void k_rscan(uint32_t* __restrict__ cntG) {
    __shared__ uint32_t tot[NBIN];
    __shared__ uint32_t gsum[256];
    __shared__ uint32_t gbase[256];
    int t = threadIdx.x;
    int row = blockIdx.x;
    uint32_t* base = cntG + (size_t)row * NSEG * NBIN;
    uint32_t loc = 0;
    #pragma unroll
    for (int k = 0; k < NBIN / 256; ++k) {
        int bn = t * (NBIN / 256) + k;
        uint32_t s = 0;
        for (int sg = 0; sg < NSEG; ++sg) s += base[sg * NBIN + bn];
        tot[bn] = s;
        loc += s;
    }
    gsum[t] = loc;
    __syncthreads();
    if (t == 0) {
        uint32_t acc = 0;
        for (int i = 0; i < 256; ++i) { uint32_t v = gsum[i]; gbase[i] = acc; acc += v; }
    }
    __syncthreads();
    uint32_t run = gbase[t];
    #pragma unroll
    for (int k = 0; k < NBIN / 256; ++k) {
        int bn = t * (NBIN / 256) + k;
        uint32_t tv = tot[bn];
        uint32_t r2 = run;
        for (int sg = 0; sg < NSEG; ++sg) {
            uint32_t cv = base[sg * NBIN + bn];
            base[sg * NBIN + bn] = r2;
            r2 += cv;
        }
        run += tv;
    }
}

// ---------- K6b-3: stable scatter (11-bit): ballot rank + cross-wave prefix + running base ----------
__global__ __launch_bounds__(256) void k_rscatter(const uint64_t* __restrict__ in, uint64_t* __restrict__ out,
                                                  const uint32_t* __restrict__ cntG, int shift) {
    __shared__ uint16_t wcnt[4][NBIN];
    __shared__ uint32_t runbase[NBIN];
    int t = threadIdx.x;
    int w = t >> 6, lane = t & 63;
    int seg = blockIdx.x, row = blockIdx.y;
    const uint32_t* cbase = cntG + ((size_t)row * NSEG + seg) * NBIN;
    #pragma unroll
    for (int k = 0; k < NBIN / 256; ++k) runbase[k * 256 + t] = cbase[k * 256 + t];
    const uint64_t* src = in + (size_t)row * HW + (size_t)seg * SEGN;
    uint64_t* dst = out + (size_t)row * HW;
    for (int i = 0; i < SEGN / 256; ++i) {
        __syncthreads();
        #pragma unroll
        for (int k = 0; k < NBIN / 256; ++k)
            ((uint64_t*)wcnt)[k * 256 + t] = 0;      // zero 4*NBIN u16 = NBIN u64
        __syncthreads();
        uint64_t kv = src[i * 256 + t];
        unsigned d = (unsigned)(kv >> shift) & (NBIN - 1);
        uint64_t peers = ~0ull;
        #pragma unroll
        for (int bit = 0; bit < 11; ++bit) {
            uint64_t bm = __ballot((d >> bit) & 1u);
            peers &= ((d >> bit) & 1u) ? bm : ~bm;
        }
        unsigned lanerank = (unsigned)__popcll(peers & ((1ull << lane) - 1ull));
        unsigned wtotal = (unsigned)__popcll(peers);
        if (lanerank == 0) wcnt[w][d] = (uint16_t)wtotal;
        __syncthreads();
        unsigned wpre = 0;
        #pragma unroll
        for (int ww = 0; ww < 4; ++ww) {
            unsigned cv = wcnt[ww][d];
            if (ww < w) wpre += cv;
        }
        unsigned pos = runbase[d] + wpre + lanerank;
        dst[pos] = kv;
        __syncthreads();
        #pragma unroll
        for (int k = 0; k < NBIN / 256; ++k) {
            int bn = k * 256 + t;
            runbase[bn] += (uint32_t)wcnt[0][bn] + wcnt[1][bn] + wcnt[2][bn] + wcnt[3][bn];
        }
    }
}

// ---------- K6c: unpack sorted keys -> vs, idxv ----------
__global__ void k_unpack(const uint64_t* __restrict__ keys, float* __restrict__ vs, int* __restrict__ idxv) {
    int j = blockIdx.x * 256 + threadIdx.x;
    int row = blockIdx.y;
    size_t o = (size_t)row * HW + j;
    uint64_t k = keys[o];
    vs[o] = s2f((uint32_t)(k >> 32));
    idxv[o] = (int)(k & 0xFFFFFFFFull);
}

// ---------- K6d: gather q1,k1,q2,k2 into sorted order ----------
// v2: 1536 blocks x 256 thr = 6 blocks/CU (24 waves/CU). XCD swizzle keeps 16 distinct
// rows per XCD (2.3MB L2 window). Per thread: 1 int4 index load -> 16 independent
// gathers (4 idx x 4 planes) in flight -> 4 coalesced float4 stores. No barriers.
__global__ __launch_bounds__(256) void k_gather4(const int* __restrict__ idxv, const float* __restrict__ qkv,
                                                  float* __restrict__ g4) {
    int i = blockIdx.x;
    int xcd = i & 7;
    int local = i >> 3;                          // 0..191
    int row = xcd * 16 + (local & 15);           // same-XCD blocks share a 16-row window
    int jc = local >> 4;                         // 0..11, 3072 j's per chunk
    int b = row >> 6, cg = row & 63;
    size_t S4 = (size_t)BB * CC * HW;            // 4718592
    const float* s0 = qkv + ((size_t)(b * C5) + cg) * HW;
    const float* s1 = s0 + (size_t)64 * HW;
    const float* s2 = s0 + (size_t)128 * HW;
    const float* s3 = s0 + (size_t)192 * HW;
    size_t base = (size_t)row * HW + (size_t)jc * 3072;
    const int* irow = idxv + base;
    float* d0 = g4 + base;
    float* d1 = d0 + S4;
    float* d2 = d0 + 2 * S4;
    float* d3 = d0 + 3 * S4;
    #pragma unroll
    for (int ps = 0; ps < 3; ++ps) {
        int j = ps * 1024 + threadIdx.x * 4;
        int4 p4 = *(const int4*)&irow[j];
        float4 v0, v1, v2, v3;
        v0.x = s0[p4.x]; v0.y = s0[p4.y]; v0.z = s0[p4.z]; v0.w = s0[p4.w];
        v1.x = s1[p4.x]; v1.y = s1[p4.y]; v1.z = s1[p4.z]; v1.w = s1[p4.w];
        v2.x = s2[p4.x]; v2.y = s2[p4.y]; v2.z = s2[p4.z]; v2.w = s2[p4.w];
        v3.x = s3[p4.x]; v3.y = s3[p4.y]; v3.z = s3[p4.z]; v3.w = s3[p4.w];
        *(float4*)&d0[j] = v0;
        *(float4*)&d1[j] = v1;
        *(float4*)&d2[j] = v2;
        *(float4*)&d3[j] = v3;
    }
}

// ---------- K7a: S partials + norm^2 partials, streaming from g4 ----------
__global__ __launch_bounds__(256) void k_attn_qk(const float* __restrict__ g4,
                                                 float* __restrict__ partS, float* __restrict__ partN) {
    __shared__ float Qs[16][68];
    __shared__ float Ks[16][68];
    __shared__ float nqs[4][64];
    __shared__ float nks[4][64];
    int tid = threadIdx.x;
    int ychunk = blockIdx.x;   // NCHUNK chunks of CHN
    int z = blockIdx.y;        // 16 = b(2) x h(4) x variant(2)
    int vi = z & 1, hh = (z >> 1) & 3, b = z >> 3;
    size_t S4 = (size_t)BB * CC * HW;
    const float* Q = g4 + (vi ? 2 * S4 : (size_t)0);
    const float* Kp = g4 + (vi ? 3 * S4 : S4);
    int ty = tid >> 4, tx = tid & 15;
    float acc[4][4] = {};
    float nq = 0.f, nk = 0.f;
    int d0 = tid & 63, kset = tid >> 6;
    int nbase0 = ychunk * CHN;
    for (int it = 0; it < CHN / 16; ++it) {
        int nb0 = nbase0 + it * 16;
        __syncthreads();
        #pragma unroll
        for (int l = 0; l < 4; ++l) {
            int idx = l * 256 + tid;
            int d = idx >> 4, kk = idx & 15;
            int n = nb0 + kk;
            int cch = hh * 16 + (d >> 2), f = d & 3;
            size_t off = ((size_t)(b * CC) + cch) * HW + (vi ? (size_t)(n * 4 + f) : (size_t)(f * NQ + n));
            Qs[kk][d] = Q[off];
            Ks[kk][d] = Kp[off];
        }
        __syncthreads();
        #pragma unroll
        for (int kk = 0; kk < 16; ++kk) {
            float4 av = *(const float4*)&Qs[kk][ty * 4];
            float4 bv = *(const float4*)&Ks[kk][tx * 4];
            float aa[4] = {av.x, av.y, av.z, av.w};
            float bb[4] = {bv.x, bv.y, bv.z, bv.w};
            #pragma unroll
            for (int i = 0; i < 4; ++i)
                #pragma unroll
                for (int j = 0; j < 4; ++j)
                    acc[i][j] = fmaf(aa[i], bb[j], acc[i][j]);
        }
        #pragma unroll
        for (int kk2 = 0; kk2 < 4; ++kk2) {
            float qv = Qs[kset * 4 + kk2][d0];
            float kv = Ks[kset * 4 + kk2][d0];
            nq = fmaf(qv, qv, nq);
            nk = fmaf(kv, kv, nk);
        }
    }
    size_t sb = ((size_t)z * NCHUNK + ychunk) * 4096;
    #pragma unroll
    for (int i = 0; i < 4; ++i)
        #pragma unroll
        for (int j = 0; j < 4; ++j)
            partS[sb + (size_t)(ty * 4 + i) * 64 + tx * 4 + j] = acc[i][j];
    nqs[kset][d0] = nq;
    nks[kset][d0] = nk;
    __syncthreads();
    if (tid < 64) {
        float sq = nqs[0][tid] + nqs[1][tid] + nqs[2][tid] + nqs[3][tid];
        float sk = nks[0][tid] + nks[1][tid] + nks[2][tid] + nks[3][tid];
        size_t nb2 = ((size_t)z * NCHUNK + ychunk) * 128;
        partN[nb2 + tid] = sq;
        partN[nb2 + 64 + tid] = sk;
    }
}

// ---------- K7b: reduce partials, normalize, exp, denom = rowsum+1 ; write attn^T ----------
__global__ __launch_bounds__(256) void k_attn_softmax(const float* __restrict__ partS,
                                                      const float* __restrict__ partN,
                                                      const float* __restrict__ temp, float* __restrict__ attnT) {
    __shared__ float nqv[64], nkv[64];
    __shared__ float pbuf[64][65];
    __shared__ float rred[64][4];
    __shared__ float rsum[64];
    int tid = threadIdx.x;
    int z = blockIdx.x;
    int hh = (z >> 1) & 3;
    if (tid < 128) {
        float s = 0.f;
        for (int ch = 0; ch < NCHUNK; ++ch) s += partN[((size_t)z * NCHUNK + ch) * 128 + tid];
        float nv = fmaxf(sqrtf(s), 1e-12f);
        if (tid < 64) nqv[tid] = nv; else nkv[tid - 64] = nv;
    }
    __syncthreads();
    float tf = temp[hh];
    int d = tid >> 2, qq = tid & 3;
    float psum = 0.f;
    for (int e = qq * 16; e < qq * 16 + 16; ++e) {
        float s = 0.f;
        for (int ch = 0; ch < NCHUNK; ++ch) s += partS[((size_t)z * NCHUNK + ch) * 4096 + (size_t)d * 64 + e];
        float p = expf(tf * s / (nqv[d] * nkv[e]));
        pbuf[d][e] = p;
        psum += p;
    }
    rred[d][qq] = psum;
    __syncthreads();
    if (tid < 64) rsum[tid] = rred[tid][0] + rred[tid][1] + rred[tid][2] + rred[tid][3] + 1.0f;
    __syncthreads();
    for (int e = qq * 16; e < qq * 16 + 16; ++e)
        attnT[(size_t)z * 4096 + (size_t)e * 64 + d] = pbuf[d][e] / rsum[d];
}

// ---------- K7c: O = attn * V, written back to (c, sorted-position) layout ----------
__global__ __launch_bounds__(256) void k_attn_av(const float* __restrict__ attnT, const float* __restrict__ vs,
                                                 float* __restrict__ O1, float* __restrict__ O2) {
    __shared__ float at_s[4096];
    int tid = threadIdx.x;
    int z = blockIdx.y;
    int vi = z & 1, hh = (z >> 1) & 3, b = z >> 3;
    for (int l = 0; l < 16; ++l) at_s[l * 256 + tid] = attnT[(size_t)z * 4096 + l * 256 + tid];
    __syncthreads();
    int n = blockIdx.x * 256 + tid;
    float acc[64];
    #pragma unroll
    for (int d = 0; d < 64; ++d) acc[d] = 0.f;
    for (int e = 0; e < 64; ++e) {
        int cch = hh * 16 + (e >> 2), f = e & 3;
        size_t p = vi ? (size_t)(n * 4 + f) : (size_t)(f * NQ + n);
        float vv = vs[((size_t)(b * CC) + cch) * HW + p];
        const float* ar = &at_s[e * 64];
        #pragma unroll
        for (int d4 = 0; d4 < 16; ++d4) {
            float4 a4 = *(const float4*)&ar[d4 * 4];
            acc[d4 * 4 + 0] = fmaf(a4.x, vv, acc[d4 * 4 + 0]);
            acc[d4 * 4 + 1] = fmaf(a4.y, vv, acc[d4 * 4 + 1]);
            acc[d4 * 4 + 2] = fmaf(a4.z, vv, acc[d4 * 4 + 2]);
            acc[d4 * 4 + 3] = fmaf(a4.w, vv, acc[d4 * 4 + 3]);
        }
    }
    float* Ob = vi ? O2 : O1;
    #pragma unroll
    for (int d = 0; d < 64; ++d) {
        int cch = hh * 16 + (d >> 2), f = d & 3;
        size_t p = vi ? (size_t)(n * 4 + f) : (size_t)(f * NQ + n);
        Ob[((size_t)(b * CC) + cch) * HW + p] = acc[d];
    }
}

// ---------- K8: product in sorted domain, scatter to original positions via idxv ----------
__global__ void k_prod_scatter(const float* __restrict__ O1, const float* __restrict__ O2,
                               const int* __restrict__ idxv, float* __restrict__ pu) {
    int j = blockIdx.x * 256 + threadIdx.x;
    int row = blockIdx.y;
    size_t o = (size_t)row * HW + j;
    int p = idxv[o];
    pu[(size_t)row * HW + p] = O1[o] * O2[o];
}

// ---------- K9: proj GEMM 64x64 ----------
__global__ __launch_bounds__(256) void k_gemm_proj(const float* __restrict__ wp, const float* __restrict__ pu,
                                                   float* __restrict__ op) {
    __shared__ float wt[4096];  // wt[c*64+m] = wp[m*64+c]
    int tid = threadIdx.x;
    for (int l = 0; l < 16; ++l) {
        int i = l * 256 + tid;
        int m = i >> 6, c = i & 63;
        wt[c * 64 + m] = wp[i];
    }
    __syncthreads();
    int b = blockIdx.y;
    int n = blockIdx.x * 256 + tid;
    float acc[64];
    #pragma unroll
    for (int m = 0; m < 64; ++m) acc[m] = 0.f;
    const float* src = pu + (size_t)(b * CC) * HW + n;
    for (int c = 0; c < 64; ++c) {
        float xv = src[(size_t)c * HW];
        const float* wr = &wt[c * 64];
        #pragma unroll
        for (int m4 = 0; m4 < 16; ++m4) {
            float4 w4 = *(const float4*)&wr[m4 * 4];
            acc[m4 * 4 + 0] = fmaf(w4.x, xv, acc[m4 * 4 + 0]);
            acc[m4 * 4 + 1] = fmaf(w4.y, xv, acc[m4 * 4 + 1]);
            acc[m4 * 4 + 2] = fmaf(w4.z, xv, acc[m4 * 4 + 2]);
            acc[m4 * 4 + 3] = fmaf(w4.w, xv, acc[m4 * 4 + 3]);
        }
    }
    float* dst = op + (size_t)(b * CC) * HW + n;
    for (int m = 0; m < 64; ++m) dst[(size_t)m * HW] = acc[m];
}

// ---------- K10: spatial unsort scatter for c<32, copy c>=32 ----------
__global__ void k_final(const float* __restrict__ op, const int* __restrict__ idx_h,
                        const int* __restrict__ idx_w, float* __restrict__ out) {
    int i = blockIdx.x * 256 + threadIdx.x;
    int p = i % HW;
    int c = (i / HW) % CC;
    int b = i / (HW * CC);
    float v = op[i];
    if (c < CHF) {
        int h = p / IMW, w = p % IMW;
        size_t ib = ((size_t)(b * CHF) + c) * HW;
        int W0 = idx_w[ib + h * IMW + w];
        int H0 = idx_h[ib + h * IMW + W0];
        out[((size_t)(b * CC) + c) * HW + H0 * IMW + W0] = v;
    } else {
        out[i] = v;
    }
}

extern "C" void kernel_launch(void* const* d_in, const int* in_sizes, int n_in,
                              void* d_out, int out_size, void* d_ws, size_t ws_size,
                              hipStream_t stream) {
    (void)in_sizes; (void)n_in; (void)out_size; (void)ws_size;
    const float* x    = (const float*)d_in[0];
    const float* temp = (const float*)d_in[1];
    const float* wq   = (const float*)d_in[2];
    const float* wd3  = (const float*)d_in[3];
    const float* wd5  = (const float*)d_in[4];
    const float* wd7  = (const float*)d_in[5];
    const float* wf   = (const float*)d_in[6];
    const float* bf   = (const float*)d_in[7];
    const float* wp   = (const float*)d_in[8];
    float* out = (float*)d_out;
    float* ws = (float*)d_ws;

    // ---- workspace arena: peak 59,768,832 floats (~228 MiB) ----
    int*      idx_h = (int*)(ws + 0);
    int*      idx_w = (int*)(ws + 2359296);
    float*    A     = ws + 4718592;
    float*    slice = ws + 4718592;                    // over dead A
    float*    q     = ws + 12582912;
    float*    qkv   = ws + 36175872;
    uint64_t* keyA  = (uint64_t*)(ws + 12582912);      // over dead q
    uint64_t* keyB  = (uint64_t*)(ws + 22020096);
    float*    vs    = ws + 31457280;
    uint32_t* cntG  = (uint32_t*)(ws + 4718592);       // 128*16*2048 u32 (over dead slice)
    int*      idxv  = (int*)(ws + 4718592);            // after radix (over dead cntG)
    float*    g4    = ws + 12582912;                   // over dead keyA+keyB
    float*    O1    = ws + 36175872;                   // over dead qkv
    float*    O2    = ws + 40894464;
    float*    pu    = ws + 45613056;
    float*    op    = ws + 50331648;                   // ends 55050240
    float*    partS = ws + 55050240;                   // 2097152
    float*    partN = ws + 57147392;                   // 65536
    float*    attnT = ws + 57212928;                   // 65536 -> ends 57278464

    k_copy_back<<<9216, 256, 0, stream>>>(x, A);
    k_sort_h<<<12288, 128, 0, stream>>>(x, A, idx_h);
    k_sort_w<<<12288, 128, 0, stream>>>(A, idx_w);
    k_gemm_q<<<dim3(576, 5, 2), 256, 0, stream>>>(wq, A, q);

    for (int g = 0; g < 3; ++g) {
        for (int chunk = 0; chunk < 3; ++chunk) {
            int r0 = chunk * CROWS;
            if (g == 0)      k_dwconv<3><<<dim3(12, 320, 2), 256, 0, stream>>>(q, wd3, slice, r0);
            else if (g == 1) k_dwconv<5><<<dim3(12, 320, 2), 256, 0, stream>>>(q, wd5, slice, r0);
            else             k_dwconv<7><<<dim3(12, 320, 2), 256, 0, stream>>>(q, wd7, slice, r0);
            k_gemm_fuse<<<dim3(96, 5, 2), 256, 0, stream>>>(wf, slice, bf, qkv, g, r0);
        }
    }

    k_build_keys<<<dim3(144, 128), 256, 0, stream>>>(qkv, keyA);
    // 3 stable LSD passes of 11 bits over the value (bits 32..63); final result in keyB
    const int shifts[3] = {32, 43, 54};
    for (int p = 0; p < 3; ++p) {
        const uint64_t* src = (p & 1) ? keyB : keyA;
        uint64_t*       dst = (p & 1) ? keyA : keyB;
        k_rcount  <<<dim3(NSEG, 128), 256, 0, stream>>>(src, cntG, shifts[p]);
        k_rscan   <<<128, 256, 0, stream>>>(cntG);
        k_rscatter<<<dim3(NSEG, 128), 256, 0, stream>>>(src, dst, cntG, shifts[p]);
    }
    k_unpack<<<dim3(144, 128), 256, 0, stream>>>(keyB, vs, idxv);
    k_gather4<<<1536, 256, 0, stream>>>(idxv, qkv, g4);

    k_attn_qk<<<dim3(NCHUNK, 16), 256, 0, stream>>>(g4, partS, partN);
    k_attn_softmax<<<16, 256, 0, stream>>>(partS, partN, temp, attnT);
    k_attn_av<<<dim3(36, 16), 256, 0, stream>>>(attnT, vs, O1, O2);

    k_prod_scatter<<<dim3(144, 128), 256, 0, stream>>>(O1, O2, idxv, pu);
    k_gemm_proj<<<dim3(144, 2), 256, 0, stream>>>(wp, pu, op);
    k_final<<<18432, 256, 0, stream>>>(op, idx_h, idx_w, out);
}

// Round 3
// 1638.255 us; speedup vs baseline: 1.0070x; 1.0070x over previous
//
#include <hip/hip_runtime.h>
#include <stdint.h>
#include <stddef.h>

constexpr int IMH = 192;
constexpr int IMW = 192;
constexpr int HW  = 36864;   // 192*192
constexpr int BB  = 2;
constexpr int CC  = 64;
constexpr int CHF = 32;      // half channels (sorted part)
constexpr int C5  = 320;     // 5*CC
constexpr int NQ  = 9216;    // HW/4
constexpr int CROWS = 64;    // fuse-pipeline chunk rows
constexpr int CHWN  = CROWS * IMW;  // 12288 cols per chunk
constexpr int NCHUNK = 32;   // attn_qk n-chunks per z
constexpr int CHN = HW / 4 / NCHUNK;  // 288 n per chunk
constexpr int NSEG = 16;     // radix segments per row
constexpr int SEGN = HW / NSEG;      // 2304 elements per segment (= 9 * 256)
constexpr int NBIN = 2048;   // 11-bit radix

typedef float fx4 __attribute__((ext_vector_type(4)));  // native vector for nontemporal builtins

// ---------- float <-> monotone uint32 (order-preserving, invertible) ----------
static __device__ __forceinline__ uint32_t f2s(float f) {
    uint32_t u = __float_as_uint(f);
    return (u & 0x80000000u) ? ~u : (u | 0x80000000u);
}
static __device__ __forceinline__ float s2f(uint32_t s) {
    uint32_t u = (s & 0x80000000u) ? (s & 0x7FFFFFFFu) : ~s;
    return __uint_as_float(u);
}

// ---------- bitonic sort of 256 u64 keys in LDS (128 threads) ----------
static __device__ void bitonic256(uint64_t* keys, int tid) {
    for (unsigned k = 2; k <= 256; k <<= 1) {
        for (unsigned j = k >> 1; j; j >>= 1) {
            __syncthreads();
            unsigned i = ((tid & ~(j - 1)) << 1) | (tid & (j - 1));
            unsigned p = i | j;
            bool up = ((i & k) == 0);
            uint64_t a = keys[i], b = keys[p];
            if ((a > b) == up) { keys[i] = b; keys[p] = a; }
        }
    }
    __syncthreads();
}

// ---------- K0: copy unsorted half channels into A ----------
__global__ void k_copy_back(const float* __restrict__ x, float* __restrict__ A) {
    int i = blockIdx.x * 256 + threadIdx.x;        // over BB*CHF*HW
    int b = i / (CHF * HW);
    int r = i % (CHF * HW);
    size_t o = ((size_t)(b * CC) + CHF) * HW + r;
    A[o] = x[o];
}

// ---------- K1: stable sort along H (per b,c,w column), write A + idx_h ----------
__global__ __launch_bounds__(128) void k_sort_h(const float* __restrict__ x, float* __restrict__ A,
                                                int* __restrict__ idx_h) {
    __shared__ uint64_t keys[256];
    int tid = threadIdx.x;
    int blk = blockIdx.x;
    int w = blk % IMW;
    int c = (blk / IMW) % CHF;
    int b = blk / (IMW * CHF);
    const float* col = x + ((size_t)(b * CC) + c) * HW + w;
    for (int i = tid; i < 256; i += 128)
        keys[i] = (i < IMH) ? ((((uint64_t)f2s(col[(size_t)i * IMW])) << 32) | (uint32_t)i) : ~0ull;
    bitonic256(keys, tid);
    float* ocol = A + ((size_t)(b * CC) + c) * HW + w;
    int* icol = idx_h + ((size_t)(b * CHF) + c) * HW + w;
    for (int i = tid; i < IMH; i += 128) {
        uint64_t k = keys[i];
        ocol[(size_t)i * IMW] = s2f((uint32_t)(k >> 32));
        icol[(size_t)i * IMW] = (int)(k & 0xFFFFFFFFull);
    }
}

// ---------- K2: stable sort along W (per b,c,h row), in-place on A, write idx_w ----------
__global__ __launch_bounds__(128) void k_sort_w(float* __restrict__ A, int* __restrict__ idx_w) {
    __shared__ uint64_t keys[256];
    int tid = threadIdx.x;
    int blk = blockIdx.x;
    int h = blk % IMH;
    int c = (blk / IMH) % CHF;
    int b = blk / (IMH * CHF);
    float* row = A + ((size_t)(b * CC) + c) * HW + (size_t)h * IMW;
    for (int i = tid; i < 256; i += 128)
        keys[i] = (i < IMW) ? ((((uint64_t)f2s(row[i])) << 32) | (uint32_t)i) : ~0ull;
    bitonic256(keys, tid);
    int* irow = idx_w + ((size_t)(b * CHF) + c) * HW + (size_t)h * IMW;
    for (int i = tid; i < IMW; i += 128) {
        uint64_t k = keys[i];
        row[i] = s2f((uint32_t)(k >> 32));
        irow[i] = (int)(k & 0xFFFFFFFFull);
    }
}

// ---------- K3: q = W_qkv(320x64) * A(64xHW) per batch ----------
__global__ __launch_bounds__(256) void k_gemm_q(const float* __restrict__ wq, const float* __restrict__ A,
                                                float* __restrict__ q) {
    __shared__ float Wt[64][68];
    __shared__ float Xt[64][68];
    int tid = threadIdx.x;
    int n0 = blockIdx.x * 64, m0 = blockIdx.y * 64, b = blockIdx.z;
    for (int l = 0; l < 16; ++l) {
        int idx = l * 256 + tid;
        int cc = idx & 63, m = idx >> 6;
        Wt[cc][m] = wq[(size_t)(m0 + m) * 64 + cc];
    }
    for (int l = 0; l < 16; ++l) {
        int idx = l * 256 + tid;
        int n = idx & 63, cc = idx >> 6;
        Xt[cc][n] = A[((size_t)(b * CC) + cc) * HW + n0 + n];
    }
    __syncthreads();
    int ty = tid >> 4, tx = tid & 15;
    float acc[4][4] = {};
    for (int cc = 0; cc < 64; ++cc) {
        float4 av = *(const float4*)&Wt[cc][ty * 4];
        float4 bv = *(const float4*)&Xt[cc][tx * 4];
        float aa[4] = {av.x, av.y, av.z, av.w};
        float bb[4] = {bv.x, bv.y, bv.z, bv.w};
        #pragma unroll
        for (int i = 0; i < 4; ++i)
            #pragma unroll
            for (int j = 0; j < 4; ++j)
                acc[i][j] = fmaf(aa[i], bb[j], acc[i][j]);
    }
    for (int i = 0; i < 4; ++i) {
        float4 o;
        o.x = acc[i][0]; o.y = acc[i][1]; o.z = acc[i][2]; o.w = acc[i][3];
        *(float4*)&q[((size_t)(b * C5) + m0 + ty * 4 + i) * HW + n0 + tx * 4] = o;
    }
}

// ---------- K4: depthwise conv KSxKS (zero pad) for a 64-row chunk starting at r0 ----------
template <int KS>
__global__ __launch_bounds__(256) void k_dwconv(const float* __restrict__ q, const float* __restrict__ wd,
                                                float* __restrict__ slice, int r0) {
    constexpr int PAD = KS / 2;
    constexpr int EXT = 32 + 2 * PAD;
    __shared__ float tile[EXT][EXT];
    int tid = threadIdx.x;
    int b = blockIdx.z, c = blockIdx.y;
    int t = blockIdx.x;                  // 12 tiles: 2 tile-rows x 6 tile-cols
    int ty0 = r0 + (t / 6) * 32, tx0 = (t % 6) * 32;
    const float* src = q + ((size_t)(b * C5) + c) * HW;
    for (int i = tid; i < EXT * EXT; i += 256) {
        int iy = i / EXT, ix = i % EXT;
        int gy = ty0 + iy - PAD, gx = tx0 + ix - PAD;
        float v = 0.f;
        if (gy >= 0 && gy < IMH && gx >= 0 && gx < IMW) v = src[gy * IMW + gx];
        tile[iy][ix] = v;
    }
    __syncthreads();
    float wreg[KS * KS];
    #pragma unroll
    for (int i = 0; i < KS * KS; ++i) wreg[i] = wd[(size_t)c * KS * KS + i];
    float* dst = slice + ((size_t)(b * C5) + c) * CHWN;
    #pragma unroll
    for (int k = 0; k < 4; ++k) {
        int pix = k * 256 + tid;
        int py = pix >> 5, px = pix & 31;
        float acc = 0.f;
        #pragma unroll
        for (int ky = 0; ky < KS; ++ky)
            #pragma unroll
            for (int kx = 0; kx < KS; ++kx)
                acc = fmaf(tile[py + ky][px + kx], wreg[ky * KS + kx], acc);
        dst[(ty0 - r0 + py) * IMW + tx0 + px] = acc;
    }
}

// ---------- K5: qkv(chunk) (+)= W_fuse[:, g*320:(g+1)*320] * slice(chunk) ----------
// v3: 64x128 tile (960 blocks = 3.75/CU), 16x16 threads, 4m x 8n per thread,
// unit-stride LDS staging (conflict-free writes), LDS double-buffer, 1 barrier/iter.
__global__ __launch_bounds__(256) void k_gemm_fuse(const float* __restrict__ wf, const float* __restrict__ slice,
                                                   const float* __restrict__ bias, float* __restrict__ qkv,
                                                   int g, int r0) {
    __shared__ float Wt[2][16][68];
    __shared__ float Xt[2][16][132];
    int tid = threadIdx.x;
    int n0 = blockIdx.x * 128, m0 = blockIdx.y * 64, b = blockIdx.z;
    int gk = g * 320;
    int ty = tid >> 4, tx = tid & 15;                    // 16 x 16
    int wm = tid >> 2, wkq = (tid & 3) << 2;             // W stage: m = tid>>2, 4 consecutive kk
    int xkk = tid >> 5, xn = (tid & 31) * 4;             // X stage: kk = tid>>5 (+8), 4 consecutive n
    float acc[4][8] = {};

    const float* wsrc0 = &wf[(size_t)(m0 + wm) * 960 + gk + wkq];
    const float* xsrc0 = &slice[((size_t)(b * C5) + xkk) * CHWN + n0 + xn];

    float4 pw  = *(const float4*)wsrc0;
    float4 pxa = *(const float4*)xsrc0;
    float4 pxb = *(const float4*)(xsrc0 + (size_t)8 * CHWN);
    Wt[0][wkq + 0][wm] = pw.x;
    Wt[0][wkq + 1][wm] = pw.y;
    Wt[0][wkq + 2][wm] = pw.z;
    Wt[0][wkq + 3][wm] = pw.w;
    *(float4*)&Xt[0][xkk][xn]     = pxa;
    *(float4*)&Xt[0][xkk + 8][xn] = pxb;
    __syncthreads();

    int cur = 0;
    for (int k0 = 0; k0 < 320; k0 += 16) {
        bool more = (k0 + 16) < 320;
        if (more) {
            pw  = *(const float4*)(wsrc0 + (k0 + 16));
            const float* xsrc = xsrc0 + (size_t)(k0 + 16) * CHWN;
            pxa = *(const float4*)xsrc;
            pxb = *(const float4*)(xsrc + (size_t)8 * CHWN);
        }
        #pragma unroll
        for (int kk = 0; kk < 16; ++kk) {
            float4 av = *(const float4*)&Wt[cur][kk][ty * 4];
            float4 b0 = *(const float4*)&Xt[cur][kk][tx * 4];
            float4 b1 = *(const float4*)&Xt[cur][kk][64 + tx * 4];
            float aa[4] = {av.x, av.y, av.z, av.w};
            float bb[8] = {b0.x, b0.y, b0.z, b0.w, b1.x, b1.y, b1.z, b1.w};
            #pragma unroll
            for (int i = 0; i < 4; ++i)
                #pragma unroll
                for (int j = 0; j < 8; ++j)
                    acc[i][j] = fmaf(aa[i], bb[j], acc[i][j]);
        }
        if (more) {
            int nx = cur ^ 1;
            Wt[nx][wkq + 0][wm] = pw.x;
            Wt[nx][wkq + 1][wm] = pw.y;
            Wt[nx][wkq + 2][wm] = pw.z;
            Wt[nx][wkq + 3][wm] = pw.w;
            *(float4*)&Xt[nx][xkk][xn]     = pxa;
            *(float4*)&Xt[nx][xkk + 8][xn] = pxb;
            cur = nx;
            __syncthreads();
        }
    }

    #pragma unroll
    for (int i = 0; i < 4; ++i) {
        int m = m0 + ty * 4 + i;
        size_t base = ((size_t)(b * C5) + m) * HW + (size_t)r0 * IMW + n0;
        float* p0 = &qkv[base + tx * 4];
        float* p1 = &qkv[base + 64 + tx * 4];
        if (g == 0) {
            float bv = bias[m];
            float4 o0, o1;
            o0.x = acc[i][0] + bv; o0.y = acc[i][1] + bv; o0.z = acc[i][2] + bv; o0.w = acc[i][3] + bv;
            o1.x = acc[i][4] + bv; o1.y = acc[i][5] + bv; o1.z = acc[i][6] + bv; o1.w = acc[i][7] + bv;
            *(float4*)p0 = o0;
            *(float4*)p1 = o1;
        } else {
            float4 c0 = *(const float4*)p0;
            float4 c1 = *(const float4*)p1;
            c0.x += acc[i][0]; c0.y += acc[i][1]; c0.z += acc[i][2]; c0.w += acc[i][3];
            c1.x += acc[i][4]; c1.y += acc[i][5]; c1.z += acc[i][6]; c1.w += acc[i][7];
            *(float4*)p0 = c0;
            *(float4*)p1 = c1;
        }
    }
}

// ---------- K6a: build (value || index) u64 keys for v rows ----------
__global__ void k_build_keys(const float* __restrict__ qkv, uint64_t* __restrict__ keyA) {
    int j = blockIdx.x * 256 + threadIdx.x;
    int row = blockIdx.y;               // b*64+c
    int b = row >> 6, c = row & 63;
    float v = qkv[((size_t)(b * C5) + 256 + c) * HW + j];
    keyA[(size_t)row * HW + j] = (((uint64_t)f2s(v)) << 32) | (uint32_t)j;
}

// ---------- K6b-1: per-(row,seg) 11-bit digit histogram ----------
__global__ __launch_bounds__(256) void k_rcount(const uint64_t* __restrict__ in, uint32_t* __restrict__ cntG,
                                                int shift) {
    __shared__ uint32_t hist[NBIN];
    int t = threadIdx.x;
    int seg = blockIdx.x, row = blockIdx.y;
    #pragma unroll
    for (int k = 0; k < NBIN / 256; ++k) hist[k * 256 + t] = 0;
    __syncthreads();
    const uint64_t* src = in + (size_t)row * HW + (size_t)seg * SEGN;
    #pragma unroll
    for (int i = 0; i < SEGN / 256; ++i) {
        unsigned d = (unsigned)(src[i * 256 + t] >> shift) & (NBIN - 1);
        atomicAdd(&hist[d], 1u);
    }
    __syncthreads();
    uint32_t* dstc = cntG + ((size_t)row * NSEG + seg) * NBIN;
    #pragma unroll
    for (int k = 0; k < NBIN / 256; ++k) dstc[k * 256 + t] = hist[k * 256 + t];
}

// ---------- K6b-2: per-row two-level scan -> absolute dest base per (seg,digit) ----------
__global__ __launch_bounds__(256) void k_rscan(uint32_t* __restrict__ cntG) {
    __shared__ uint32_t tot[NBIN];
    __shared__ uint32_t gsum[256];
    __shared__ uint32_t gbase[256];
    int t = threadIdx.x;
    int row = blockIdx.x;
    uint32_t* base = cntG + (size_t)row * NSEG * NBIN;
    uint32_t loc = 0;
    #pragma unroll
    for (int k = 0; k < NBIN / 256; ++k) {
        int bn = t * (NBIN / 256) + k;
        uint32_t s = 0;
        for (int sg = 0; sg < NSEG; ++sg) s += base[sg * NBIN + bn];
        tot[bn] = s;
        loc += s;
    }
    gsum[t] = loc;
    __syncthreads();
    if (t == 0) {
        uint32_t acc = 0;
        for (int i = 0; i < 256; ++i) { uint32_t v = gsum[i]; gbase[i] = acc; acc += v; }
    }
    __syncthreads();
    uint32_t run = gbase[t];
    #pragma unroll
    for (int k = 0; k < NBIN / 256; ++k) {
        int bn = t * (NBIN / 256) + k;
        uint32_t tv = tot[bn];
        uint32_t r2 = run;
        for (int sg = 0; sg < NSEG; ++sg) {
            uint32_t cv = base[sg * NBIN + bn];
            base[sg * NBIN + bn] = r2;
            r2 += cv;
        }
        run += tv;
    }
}

// ---------- K6b-3: stable scatter (11-bit): ballot rank + cross-wave prefix + running base ----------
__global__ __launch_bounds__(256) void k_rscatter(const uint64_t* __restrict__ in, uint64_t* __restrict__ out,
                                                  const uint32_t* __restrict__ cntG, int shift) {
    __shared__ uint16_t wcnt[4][NBIN];
    __shared__ uint32_t runbase[NBIN];
    int t = threadIdx.x;
    int w = t >> 6, lane = t & 63;
    int seg = blockIdx.x, row = blockIdx.y;
    const uint32_t* cbase = cntG + ((size_t)row * NSEG + seg) * NBIN;
    #pragma unroll
    for (int k = 0; k < NBIN / 256; ++k) runbase[k * 256 + t] = cbase[k * 256 + t];
    const uint64_t* src = in + (size_t)row * HW + (size_t)seg * SEGN;
    uint64_t* dst = out + (size_t)row * HW;
    for (int i = 0; i < SEGN / 256; ++i) {
        __syncthreads();
        #pragma unroll
        for (int k = 0; k < NBIN / 256; ++k)
            ((uint64_t*)wcnt)[k * 256 + t] = 0;      // zero 4*NBIN u16 = NBIN u64
        __syncthreads();
        uint64_t kv = src[i * 256 + t];
        unsigned d = (unsigned)(kv >> shift) & (NBIN - 1);
        uint64_t peers = ~0ull;
        #pragma unroll
        for (int bit = 0; bit < 11; ++bit) {
            uint64_t bm = __ballot((d >> bit) & 1u);
            peers &= ((d >> bit) & 1u) ? bm : ~bm;
        }
        unsigned lanerank = (unsigned)__popcll(peers & ((1ull << lane) - 1ull));
        unsigned wtotal = (unsigned)__popcll(peers);
        if (lanerank == 0) wcnt[w][d] = (uint16_t)wtotal;
        __syncthreads();
        unsigned wpre = 0;
        #pragma unroll
        for (int ww = 0; ww < 4; ++ww) {
            unsigned cv = wcnt[ww][d];
            if (ww < w) wpre += cv;
        }
        unsigned pos = runbase[d] + wpre + lanerank;
        dst[pos] = kv;
        __syncthreads();
        #pragma unroll
        for (int k = 0; k < NBIN / 256; ++k) {
            int bn = k * 256 + t;
            runbase[bn] += (uint32_t)wcnt[0][bn] + wcnt[1][bn] + wcnt[2][bn] + wcnt[3][bn];
        }
    }
}

// ---------- K6c: unpack sorted keys -> vs, idxv ----------
__global__ void k_unpack(const uint64_t* __restrict__ keys, float* __restrict__ vs, int* __restrict__ idxv) {
    int j = blockIdx.x * 256 + threadIdx.x;
    int row = blockIdx.y;
    size_t o = (size_t)row * HW + j;
    uint64_t k = keys[o];
    vs[o] = s2f((uint32_t)(k >> 32));
    idxv[o] = (int)(k & 0xFFFFFFFFull);
}

// ---------- K6d: gather q1,k1,q2,k2 into sorted order ----------
// v3: phase-major (one source plane at a time across the whole XCD -> 16 rows x 144KB
// = 2.3MB L2 window per phase, like v1) + v2's wins: idx loaded ONCE into registers
// (3 x int4 per thread), 12 independent gathers in flight per phase, 6 blocks/CU,
// nontemporal streaming stores so the output stream doesn't evict the gather window.
__global__ __launch_bounds__(256) void k_gather4(const int* __restrict__ idxv, const float* __restrict__ qkv,
                                                  float* __restrict__ g4) {
    int i = blockIdx.x;
    int xcd = i & 7;
    int local = i >> 3;                          // 0..191
    int row = xcd * 16 + (local & 15);           // same-XCD blocks share a 16-row window
    int jc = local >> 4;                         // 0..11, 3072 j's per chunk
    int b = row >> 6, cg = row & 63;
    size_t S4 = (size_t)BB * CC * HW;            // 4718592
    size_t base = (size_t)row * HW + (size_t)jc * 3072;
    const int* irow = idxv + base;

    int j0 = threadIdx.x * 4;
    int4 p0 = *(const int4*)&irow[j0];
    int4 p1 = *(const int4*)&irow[j0 + 1024];
    int4 p2 = *(const int4*)&irow[j0 + 2048];

    const float* splane = qkv + ((size_t)(b * C5) + cg) * HW;
    float* dplane = g4 + base;
    #pragma unroll
    for (int ph = 0; ph < 4; ++ph) {
        const float* s = splane + (size_t)(ph * 64) * HW;
        fx4 v0, v1, v2;
        v0.x = s[p0.x]; v0.y = s[p0.y]; v0.z = s[p0.z]; v0.w = s[p0.w];
        v1.x = s[p1.x]; v1.y = s[p1.y]; v1.z = s[p1.z]; v1.w = s[p1.w];
        v2.x = s[p2.x]; v2.y = s[p2.y]; v2.z = s[p2.z]; v2.w = s[p2.w];
        float* d = dplane + (size_t)ph * S4;
        __builtin_nontemporal_store(v0, (fx4*)&d[j0]);
        __builtin_nontemporal_store(v1, (fx4*)&d[j0 + 1024]);
        __builtin_nontemporal_store(v2, (fx4*)&d[j0 + 2048]);
        __syncthreads();                         // keep all waves in the same phase
    }
}

// ---------- K7a: S partials + norm^2 partials, streaming from g4 ----------
__global__ __launch_bounds__(256) void k_attn_qk(const float* __restrict__ g4,
                                                 float* __restrict__ partS, float* __restrict__ partN) {
    __shared__ float Qs[16][68];
    __shared__ float Ks[16][68];
    __shared__ float nqs[4][64];
    __shared__ float nks[4][64];
    int tid = threadIdx.x;
    int ychunk = blockIdx.x;   // NCHUNK chunks of CHN
    int z = blockIdx.y;        // 16 = b(2) x h(4) x variant(2)
    int vi = z & 1, hh = (z >> 1) & 3, b = z >> 3;
    size_t S4 = (size_t)BB * CC * HW;
    const float* Q = g4 + (vi ? 2 * S4 : (size_t)0);
    const float* Kp = g4 + (vi ? 3 * S4 : S4);
    int ty = tid >> 4, tx = tid & 15;
    float acc[4][4] = {};
    float nq = 0.f, nk = 0.f;
    int d0 = tid & 63, kset = tid >> 6;
    int nbase0 = ychunk * CHN;
    for (int it = 0; it < CHN / 16; ++it) {
        int nb0 = nbase0 + it * 16;
        __syncthreads();
        #pragma unroll
        for (int l = 0; l < 4; ++l) {
            int idx = l * 256 + tid;
            int d = idx >> 4, kk = idx & 15;
            int n = nb0 + kk;
            int cch = hh * 16 + (d >> 2), f = d & 3;
            size_t off = ((size_t)(b * CC) + cch) * HW + (vi ? (size_t)(n * 4 + f) : (size_t)(f * NQ + n));
            Qs[kk][d] = Q[off];
            Ks[kk][d] = Kp[off];
        }
        __syncthreads();
        #pragma unroll
        for (int kk = 0; kk < 16; ++kk) {
            float4 av = *(const float4*)&Qs[kk][ty * 4];
            float4 bv = *(const float4*)&Ks[kk][tx * 4];
            float aa[4] = {av.x, av.y, av.z, av.w};
            float bb[4] = {bv.x, bv.y, bv.z, bv.w};
            #pragma unroll
            for (int i = 0; i < 4; ++i)
                #pragma unroll
                for (int j = 0; j < 4; ++j)
                    acc[i][j] = fmaf(aa[i], bb[j], acc[i][j]);
        }
        #pragma unroll
        for (int kk2 = 0; kk2 < 4; ++kk2) {
            float qv = Qs[kset * 4 + kk2][d0];
            float kv = Ks[kset * 4 + kk2][d0];
            nq = fmaf(qv, qv, nq);
            nk = fmaf(kv, kv, nk);
        }
    }
    size_t sb = ((size_t)z * NCHUNK + ychunk) * 4096;
    #pragma unroll
    for (int i = 0; i < 4; ++i)
        #pragma unroll
        for (int j = 0; j < 4; ++j)
            partS[sb + (size_t)(ty * 4 + i) * 64 + tx * 4 + j] = acc[i][j];
    nqs[kset][d0] = nq;
    nks[kset][d0] = nk;
    __syncthreads();
    if (tid < 64) {
        float sq = nqs[0][tid] + nqs[1][tid] + nqs[2][tid] + nqs[3][tid];
        float sk = nks[0][tid] + nks[1][tid] + nks[2][tid] + nks[3][tid];
        size_t nb2 = ((size_t)z * NCHUNK + ychunk) * 128;
        partN[nb2 + tid] = sq;
        partN[nb2 + 64 + tid] = sk;
    }
}

// ---------- K7b: reduce partials, normalize, exp, denom = rowsum+1 ; write attn^T ----------
__global__ __launch_bounds__(256) void k_attn_softmax(const float* __restrict__ partS,
                                                      const float* __restrict__ partN,
                                                      const float* __restrict__ temp, float* __restrict__ attnT) {
    __shared__ float nqv[64], nkv[64];
    __shared__ float pbuf[64][65];
    __shared__ float rred[64][4];
    __shared__ float rsum[64];
    int tid = threadIdx.x;
    int z = blockIdx.x;
    int hh = (z >> 1) & 3;
    if (tid < 128) {
        float s = 0.f;
        for (int ch = 0; ch < NCHUNK; ++ch) s += partN[((size_t)z * NCHUNK + ch) * 128 + tid];
        float nv = fmaxf(sqrtf(s), 1e-12f);
        if (tid < 64) nqv[tid] = nv; else nkv[tid - 64] = nv;
    }
    __syncthreads();
    float tf = temp[hh];
    int d = tid >> 2, qq = tid & 3;
    float psum = 0.f;
    for (int e = qq * 16; e < qq * 16 + 16; ++e) {
        float s = 0.f;
        for (int ch = 0; ch < NCHUNK; ++ch) s += partS[((size_t)z * NCHUNK + ch) * 4096 + (size_t)d * 64 + e];
        float p = expf(tf * s / (nqv[d] * nkv[e]));
        pbuf[d][e] = p;
        psum += p;
    }
    rred[d][qq] = psum;
    __syncthreads();
    if (tid < 64) rsum[tid] = rred[tid][0] + rred[tid][1] + rred[tid][2] + rred[tid][3] + 1.0f;
    __syncthreads();
    for (int e = qq * 16; e < qq * 16 + 16; ++e)
        attnT[(size_t)z * 4096 + (size_t)e * 64 + d] = pbuf[d][e] / rsum[d];
}

// ---------- K7c: O = attn * V, written back to (c, sorted-position) layout ----------
__global__ __launch_bounds__(256) void k_attn_av(const float* __restrict__ attnT, const float* __restrict__ vs,
                                                 float* __restrict__ O1, float* __restrict__ O2) {
    __shared__ float at_s[4096];
    int tid = threadIdx.x;
    int z = blockIdx.y;
    int vi = z & 1, hh = (z >> 1) & 3, b = z >> 3;
    for (int l = 0; l < 16; ++l) at_s[l * 256 + tid] = attnT[(size_t)z * 4096 + l * 256 + tid];
    __syncthreads();
    int n = blockIdx.x * 256 + tid;
    float acc[64];
    #pragma unroll
    for (int d = 0; d < 64; ++d) acc[d] = 0.f;
    for (int e = 0; e < 64; ++e) {
        int cch = hh * 16 + (e >> 2), f = e & 3;
        size_t p = vi ? (size_t)(n * 4 + f) : (size_t)(f * NQ + n);
        float vv = vs[((size_t)(b * CC) + cch) * HW + p];
        const float* ar = &at_s[e * 64];
        #pragma unroll
        for (int d4 = 0; d4 < 16; ++d4) {
            float4 a4 = *(const float4*)&ar[d4 * 4];
            acc[d4 * 4 + 0] = fmaf(a4.x, vv, acc[d4 * 4 + 0]);
            acc[d4 * 4 + 1] = fmaf(a4.y, vv, acc[d4 * 4 + 1]);
            acc[d4 * 4 + 2] = fmaf(a4.z, vv, acc[d4 * 4 + 2]);
            acc[d4 * 4 + 3] = fmaf(a4.w, vv, acc[d4 * 4 + 3]);
        }
    }
    float* Ob = vi ? O2 : O1;
    #pragma unroll
    for (int d = 0; d < 64; ++d) {
        int cch = hh * 16 + (d >> 2), f = d & 3;
        size_t p = vi ? (size_t)(n * 4 + f) : (size_t)(f * NQ + n);
        Ob[((size_t)(b * CC) + cch) * HW + p] = acc[d];
    }
}

// ---------- K8: product in sorted domain, scatter to original positions via idxv ----------
__global__ void k_prod_scatter(const float* __restrict__ O1, const float* __restrict__ O2,
                               const int* __restrict__ idxv, float* __restrict__ pu) {
    int j = blockIdx.x * 256 + threadIdx.x;
    int row = blockIdx.y;
    size_t o = (size_t)row * HW + j;
    int p = idxv[o];
    pu[(size_t)row * HW + p] = O1[o] * O2[o];
}

// ---------- K9: proj GEMM 64x64 ----------
__global__ __launch_bounds__(256) void k_gemm_proj(const float* __restrict__ wp, const float* __restrict__ pu,
                                                   float* __restrict__ op) {
    __shared__ float wt[4096];  // wt[c*64+m] = wp[m*64+c]
    int tid = threadIdx.x;
    for (int l = 0; l < 16; ++l) {
        int i = l * 256 + tid;
        int m = i >> 6, c = i & 63;
        wt[c * 64 + m] = wp[i];
    }
    __syncthreads();
    int b = blockIdx.y;
    int n = blockIdx.x * 256 + tid;
    float acc[64];
    #pragma unroll
    for (int m = 0; m < 64; ++m) acc[m] = 0.f;
    const float* src = pu + (size_t)(b * CC) * HW + n;
    for (int c = 0; c < 64; ++c) {
        float xv = src[(size_t)c * HW];
        const float* wr = &wt[c * 64];
        #pragma unroll
        for (int m4 = 0; m4 < 16; ++m4) {
            float4 w4 = *(const float4*)&wr[m4 * 4];
            acc[m4 * 4 + 0] = fmaf(w4.x, xv, acc[m4 * 4 + 0]);
            acc[m4 * 4 + 1] = fmaf(w4.y, xv, acc[m4 * 4 + 1]);
            acc[m4 * 4 + 2] = fmaf(w4.z, xv, acc[m4 * 4 + 2]);
            acc[m4 * 4 + 3] = fmaf(w4.w, xv, acc[m4 * 4 + 3]);
        }
    }
    float* dst = op + (size_t)(b * CC) * HW + n;
    for (int m = 0; m < 64; ++m) dst[(size_t)m * HW] = acc[m];
}

// ---------- K10: spatial unsort scatter for c<32, copy c>=32 ----------
__global__ void k_final(const float* __restrict__ op, const int* __restrict__ idx_h,
                        const int* __restrict__ idx_w, float* __restrict__ out) {
    int i = blockIdx.x * 256 + threadIdx.x;
    int p = i % HW;
    int c = (i / HW) % CC;
    int b = i / (HW * CC);
    float v = op[i];
    if (c < CHF) {
        int h = p / IMW, w = p % IMW;
        size_t ib = ((size_t)(b * CHF) + c) * HW;
        int W0 = idx_w[ib + h * IMW + w];
        int H0 = idx_h[ib + h * IMW + W0];
        out[((size_t)(b * CC) + c) * HW + H0 * IMW + W0] = v;
    } else {
        out[i] = v;
    }
}

extern "C" void kernel_launch(void* const* d_in, const int* in_sizes, int n_in,
                              void* d_out, int out_size, void* d_ws, size_t ws_size,
                              hipStream_t stream) {
    (void)in_sizes; (void)n_in; (void)out_size; (void)ws_size;
    const float* x    = (const float*)d_in[0];
    const float* temp = (const float*)d_in[1];
    const float* wq   = (const float*)d_in[2];
    const float* wd3  = (const float*)d_in[3];
    const float* wd5  = (const float*)d_in[4];
    const float* wd7  = (const float*)d_in[5];
    const float* wf   = (const float*)d_in[6];
    const float* bf   = (const float*)d_in[7];
    const float* wp   = (const float*)d_in[8];
    float* out = (float*)d_out;
    float* ws = (float*)d_ws;

    // ---- workspace arena: peak 59,768,832 floats (~228 MiB) ----
    int*      idx_h = (int*)(ws + 0);
    int*      idx_w = (int*)(ws + 2359296);
    float*    A     = ws + 4718592;
    float*    slice = ws + 4718592;                    // over dead A
    float*    q     = ws + 12582912;
    float*    qkv   = ws + 36175872;
    uint64_t* keyA  = (uint64_t*)(ws + 12582912);      // over dead q
    uint64_t* keyB  = (uint64_t*)(ws + 22020096);
    float*    vs    = ws + 31457280;
    uint32_t* cntG  = (uint32_t*)(ws + 4718592);       // 128*16*2048 u32 (over dead slice)
    int*      idxv  = (int*)(ws + 4718592);            // after radix (over dead cntG)
    float*    g4    = ws + 12582912;                   // over dead keyA+keyB
    float*    O1    = ws + 36175872;                   // over dead qkv
    float*    O2    = ws + 40894464;
    float*    pu    = ws + 45613056;
    float*    op    = ws + 50331648;                   // ends 55050240
    float*    partS = ws + 55050240;                   // 2097152
    float*    partN = ws + 57147392;                   // 65536
    float*    attnT = ws + 57212928;                   // 65536 -> ends 57278464

    k_copy_back<<<9216, 256, 0, stream>>>(x, A);
    k_sort_h<<<12288, 128, 0, stream>>>(x, A, idx_h);
    k_sort_w<<<12288, 128, 0, stream>>>(A, idx_w);
    k_gemm_q<<<dim3(576, 5, 2), 256, 0, stream>>>(wq, A, q);

    for (int g = 0; g < 3; ++g) {
        for (int chunk = 0; chunk < 3; ++chunk) {
            int r0 = chunk * CROWS;
            if (g == 0)      k_dwconv<3><<<dim3(12, 320, 2), 256, 0, stream>>>(q, wd3, slice, r0);
            else if (g == 1) k_dwconv<5><<<dim3(12, 320, 2), 256, 0, stream>>>(q, wd5, slice, r0);
            else             k_dwconv<7><<<dim3(12, 320, 2), 256, 0, stream>>>(q, wd7, slice, r0);
            k_gemm_fuse<<<dim3(96, 5, 2), 256, 0, stream>>>(wf, slice, bf, qkv, g, r0);
        }
    }

    k_build_keys<<<dim3(144, 128), 256, 0, stream>>>(qkv, keyA);
    // 3 stable LSD passes of 11 bits over the value (bits 32..63); final result in keyB
    const int shifts[3] = {32, 43, 54};
    for (int p = 0; p < 3; ++p) {
        const uint64_t* src = (p & 1) ? keyB : keyA;
        uint64_t*       dst = (p & 1) ? keyA : keyB;
        k_rcount  <<<dim3(NSEG, 128), 256, 0, stream>>>(src, cntG, shifts[p]);
        k_rscan   <<<128, 256, 0, stream>>>(cntG);
        k_rscatter<<<dim3(NSEG, 128), 256, 0, stream>>>(src, dst, cntG, shifts[p]);
    }
    k_unpack<<<dim3(144, 128), 256, 0, stream>>>(keyB, vs, idxv);
    k_gather4<<<1536, 256, 0, stream>>>(idxv, qkv, g4);

    k_attn_qk<<<dim3(NCHUNK, 16), 256, 0, stream>>>(g4, partS, partN);
    k_attn_softmax<<<16, 256, 0, stream>>>(partS, partN, temp, attnT);
    k_attn_av<<<dim3(36, 16), 256, 0, stream>>>(attnT, vs, O1, O2);

    k_prod_scatter<<<dim3(144, 128), 256, 0, stream>>>(O1, O2, idxv, pu);
    k_gemm_proj<<<dim3(144, 2), 256, 0, stream>>>(wp, pu, op);
    k_final<<<18432, 256, 0, stream>>>(op, idx_h, idx_w, out);
}

// Round 5
// 1235.617 us; speedup vs baseline: 1.3351x; 1.3259x over previous
//
#include <hip/hip_runtime.h>
#include <stdint.h>
#include <stddef.h>

constexpr int IMH = 192;
constexpr int IMW = 192;
constexpr int HW  = 36864;   // 192*192
constexpr int BB  = 2;
constexpr int CC  = 64;
constexpr int CHF = 32;      // half channels (sorted part)
constexpr int C5  = 320;     // 5*CC
constexpr int NQ  = 9216;    // HW/4
constexpr int CROWS = 64;    // fuse-pipeline chunk rows
constexpr int CHWN  = CROWS * IMW;  // 12288 cols per chunk
constexpr int NCHUNK = 32;   // attn_qk n-chunks per z
constexpr int CHN = HW / 4 / NCHUNK;  // 288 n per chunk
constexpr int NSEG = 16;     // radix segments per row
constexpr int SEGN = HW / NSEG;      // 2304 elements per segment (= 9 * 256)
constexpr int NBIN = 2048;   // 11-bit radix

typedef float fx4 __attribute__((ext_vector_type(4)));
typedef _Float16 f16;
typedef _Float16 f16x8 __attribute__((ext_vector_type(8)));
typedef float f32x4 __attribute__((ext_vector_type(4)));

// ---------- float <-> monotone uint32 (order-preserving, invertible) ----------
static __device__ __forceinline__ uint32_t f2s(float f) {
    uint32_t u = __float_as_uint(f);
    return (u & 0x80000000u) ? ~u : (u | 0x80000000u);
}
static __device__ __forceinline__ float s2f(uint32_t s) {
    uint32_t u = (s & 0x80000000u) ? (s & 0x7FFFFFFFu) : ~s;
    return __uint_as_float(u);
}

// ---------- bitonic sort of 256 u64 keys in LDS (128 threads) ----------
static __device__ void bitonic256(uint64_t* keys, int tid) {
    for (unsigned k = 2; k <= 256; k <<= 1) {
        for (unsigned j = k >> 1; j; j >>= 1) {
            __syncthreads();
            unsigned i = ((tid & ~(j - 1)) << 1) | (tid & (j - 1));
            unsigned p = i | j;
            bool up = ((i & k) == 0);
            uint64_t a = keys[i], b = keys[p];
            if ((a > b) == up) { keys[i] = b; keys[p] = a; }
        }
    }
    __syncthreads();
}

// ---------- K0: copy unsorted half channels into A ----------
__global__ void k_copy_back(const float* __restrict__ x, float* __restrict__ A) {
    int i = blockIdx.x * 256 + threadIdx.x;        // over BB*CHF*HW
    int b = i / (CHF * HW);
    int r = i % (CHF * HW);
    size_t o = ((size_t)(b * CC) + CHF) * HW + r;
    A[o] = x[o];
}

// ---------- K1: stable sort along H (per b,c,w column), write A + idx_h ----------
__global__ __launch_bounds__(128) void k_sort_h(const float* __restrict__ x, float* __restrict__ A,
                                                int* __restrict__ idx_h) {
    __shared__ uint64_t keys[256];
    int tid = threadIdx.x;
    int blk = blockIdx.x;
    int w = blk % IMW;
    int c = (blk / IMW) % CHF;
    int b = blk / (IMW * CHF);
    const float* col = x + ((size_t)(b * CC) + c) * HW + w;
    for (int i = tid; i < 256; i += 128)
        keys[i] = (i < IMH) ? ((((uint64_t)f2s(col[(size_t)i * IMW])) << 32) | (uint32_t)i) : ~0ull;
    bitonic256(keys, tid);
    float* ocol = A + ((size_t)(b * CC) + c) * HW + w;
    int* icol = idx_h + ((size_t)(b * CHF) + c) * HW + w;
    for (int i = tid; i < IMH; i += 128) {
        uint64_t k = keys[i];
        ocol[(size_t)i * IMW] = s2f((uint32_t)(k >> 32));
        icol[(size_t)i * IMW] = (int)(k & 0xFFFFFFFFull);
    }
}

// ---------- K2: stable sort along W (per b,c,h row), in-place on A, write idx_w ----------
__global__ __launch_bounds__(128) void k_sort_w(float* __restrict__ A, int* __restrict__ idx_w) {
    __shared__ uint64_t keys[256];
    int tid = threadIdx.x;
    int blk = blockIdx.x;
    int h = blk % IMH;
    int c = (blk / IMH) % CHF;
    int b = blk / (IMH * CHF);
    float* row = A + ((size_t)(b * CC) + c) * HW + (size_t)h * IMW;
    for (int i = tid; i < 256; i += 128)
        keys[i] = (i < IMW) ? ((((uint64_t)f2s(row[i])) << 32) | (uint32_t)i) : ~0ull;
    bitonic256(keys, tid);
    int* irow = idx_w + ((size_t)(b * CHF) + c) * HW + (size_t)h * IMW;
    for (int i = tid; i < IMW; i += 128) {
        uint64_t k = keys[i];
        row[i] = s2f((uint32_t)(k >> 32));
        irow[i] = (int)(k & 0xFFFFFFFFull);
    }
}

// ---------- K3: q = W_qkv(320x64) * A(64xHW) per batch ----------
__global__ __launch_bounds__(256) void k_gemm_q(const float* __restrict__ wq, const float* __restrict__ A,
                                                float* __restrict__ q) {
    __shared__ float Wt[64][68];
    __shared__ float Xt[64][68];
    int tid = threadIdx.x;
    int n0 = blockIdx.x * 64, m0 = blockIdx.y * 64, b = blockIdx.z;
    for (int l = 0; l < 16; ++l) {
        int idx = l * 256 + tid;
        int cc = idx & 63, m = idx >> 6;
        Wt[cc][m] = wq[(size_t)(m0 + m) * 64 + cc];
    }
    for (int l = 0; l < 16; ++l) {
        int idx = l * 256 + tid;
        int n = idx & 63, cc = idx >> 6;
        Xt[cc][n] = A[((size_t)(b * CC) + cc) * HW + n0 + n];
    }
    __syncthreads();
    int ty = tid >> 4, tx = tid & 15;
    float acc[4][4] = {};
    for (int cc = 0; cc < 64; ++cc) {
        float4 av = *(const float4*)&Wt[cc][ty * 4];
        float4 bv = *(const float4*)&Xt[cc][tx * 4];
        float aa[4] = {av.x, av.y, av.z, av.w};
        float bb[4] = {bv.x, bv.y, bv.z, bv.w};
        #pragma unroll
        for (int i = 0; i < 4; ++i)
            #pragma unroll
            for (int j = 0; j < 4; ++j)
                acc[i][j] = fmaf(aa[i], bb[j], acc[i][j]);
    }
    for (int i = 0; i < 4; ++i) {
        float4 o;
        o.x = acc[i][0]; o.y = acc[i][1]; o.z = acc[i][2]; o.w = acc[i][3];
        *(float4*)&q[((size_t)(b * C5) + m0 + ty * 4 + i) * HW + n0 + tx * 4] = o;
    }
}

// ---------- K4: depthwise conv KSxKS (zero pad) for a 64-row chunk starting at r0 ----------
template <int KS>
__global__ __launch_bounds__(256) void k_dwconv(const float* __restrict__ q, const float* __restrict__ wd,
                                                float* __restrict__ slice, int r0) {
    constexpr int PAD = KS / 2;
    constexpr int EXT = 32 + 2 * PAD;
    __shared__ float tile[EXT][EXT];
    int tid = threadIdx.x;
    int b = blockIdx.z, c = blockIdx.y;
    int t = blockIdx.x;                  // 12 tiles: 2 tile-rows x 6 tile-cols
    int ty0 = r0 + (t / 6) * 32, tx0 = (t % 6) * 32;
    const float* src = q + ((size_t)(b * C5) + c) * HW;
    for (int i = tid; i < EXT * EXT; i += 256) {
        int iy = i / EXT, ix = i % EXT;
        int gy = ty0 + iy - PAD, gx = tx0 + ix - PAD;
        float v = 0.f;
        if (gy >= 0 && gy < IMH && gx >= 0 && gx < IMW) v = src[gy * IMW + gx];
        tile[iy][ix] = v;
    }
    __syncthreads();
    float wreg[KS * KS];
    #pragma unroll
    for (int i = 0; i < KS * KS; ++i) wreg[i] = wd[(size_t)c * KS * KS + i];
    float* dst = slice + ((size_t)(b * C5) + c) * CHWN;
    #pragma unroll
    for (int k = 0; k < 4; ++k) {
        int pix = k * 256 + tid;
        int py = pix >> 5, px = pix & 31;
        float acc = 0.f;
        #pragma unroll
        for (int ky = 0; ky < KS; ++ky)
            #pragma unroll
            for (int kx = 0; kx < KS; ++kx)
                acc = fmaf(tile[py + ky][px + kx], wreg[ky * KS + kx], acc);
        dst[(ty0 - r0 + py) * IMW + tx0 + px] = acc;
    }
}

// ---------- K5: qkv(chunk) (+)= W_fuse[:, g*320:(g+1)*320] * slice(chunk) ----------
// v5 (MFMA f16x2, in-kernel W split): C = Wh*Xh + Wh*Xl + Wl*Xh via
// mfma_f32_16x16x32_f16 (neglected Wl*Xl term ~2^-22 rel; fp32-equivalent at K=960).
// W read as fp32 from global and split to f16 hi/lo DURING LDS staging (no
// precomputed planes -> no workspace aliasing; W tile is 8KB/k-step, L2-resident).
// B=X read per-lane direct from global in fragment order (16 lanes consecutive n =
// coalesced 64B runs) and split to f16 hi/lo in registers.
// C/D layout (m89-verified): col=lane&15 -> n, row=4*(lane>>4)+reg -> m.
// A and B use the identical per-lane k-mapping (k = (lane>>4)*8 + j), so any
// global k-permutation cancels in the contraction.
__global__ __launch_bounds__(256) void k_gemm_fuse(const float* __restrict__ wf,
                                                   const float* __restrict__ slice, const float* __restrict__ bias,
                                                   float* __restrict__ qkv, int g, int r0) {
    __shared__ f16 Ah[64][40];
    __shared__ f16 Al[64][40];
    int tid = threadIdx.x;
    int n0 = blockIdx.x * 128, m0 = blockIdx.y * 64, b = blockIdx.z;
    int lane = tid & 63, wv = tid >> 6;
    int l15 = lane & 15, lg = lane >> 4;
    int nwave = n0 + wv * 32;                 // wave's 32-col n-strip
    int sm = tid >> 2, skr = (tid & 3) * 8;   // W staging: m=tid>>2, 8 consecutive k
    int gk = g * 320;
    f32x4 acc[4][2];
    #pragma unroll
    for (int i = 0; i < 4; ++i)
        #pragma unroll
        for (int j = 0; j < 2; ++j)
            acc[i][j] = (f32x4){0.f, 0.f, 0.f, 0.f};

    const float* xcol = slice + (size_t)(b * C5) * CHWN + nwave + l15;
    const float* wrow = wf + (size_t)(m0 + sm) * 960 + gk + skr;

    for (int k0 = 0; k0 < 320; k0 += 32) {
        if (k0) __syncthreads();
        // stage W tile: fp32 -> f16 hi/lo split in registers -> LDS
        {
            float4 w0 = *(const float4*)(wrow + k0);
            float4 w1 = *(const float4*)(wrow + k0 + 4);
            float wvv[8] = {w0.x, w0.y, w0.z, w0.w, w1.x, w1.y, w1.z, w1.w};
            f16x8 hv, lv;
            #pragma unroll
            for (int j = 0; j < 8; ++j) {
                f16 h = (f16)wvv[j];
                hv[j] = h;
                lv[j] = (f16)(wvv[j] - (float)h);
            }
            *(f16x8*)&Ah[sm][skr] = hv;
            *(f16x8*)&Al[sm][skr] = lv;
        }
        float xv[2][8];
        #pragma unroll
        for (int fn = 0; fn < 2; ++fn)
            #pragma unroll
            for (int j = 0; j < 8; ++j)
                xv[fn][j] = xcol[(size_t)(k0 + lg * 8 + j) * CHWN + fn * 16];
        __syncthreads();
        f16x8 bh[2], bl[2];
        #pragma unroll
        for (int fn = 0; fn < 2; ++fn)
            #pragma unroll
            for (int j = 0; j < 8; ++j) {
                float v = xv[fn][j];
                f16 h = (f16)v;
                bh[fn][j] = h;
                bl[fn][j] = (f16)(v - (float)h);
            }
        #pragma unroll
        for (int fm = 0; fm < 4; ++fm) {
            f16x8 ah = *(const f16x8*)&Ah[fm * 16 + l15][lg * 8];
            f16x8 al = *(const f16x8*)&Al[fm * 16 + l15][lg * 8];
            #pragma unroll
            for (int fn = 0; fn < 2; ++fn) {
                acc[fm][fn] = __builtin_amdgcn_mfma_f32_16x16x32_f16(ah, bh[fn], acc[fm][fn], 0, 0, 0);
                acc[fm][fn] = __builtin_amdgcn_mfma_f32_16x16x32_f16(ah, bl[fn], acc[fm][fn], 0, 0, 0);
                acc[fm][fn] = __builtin_amdgcn_mfma_f32_16x16x32_f16(al, bh[fn], acc[fm][fn], 0, 0, 0);
            }
        }
    }

    #pragma unroll
    for (int fm = 0; fm < 4; ++fm) {
        #pragma unroll
        for (int r = 0; r < 4; ++r) {
            int m = m0 + fm * 16 + lg * 4 + r;
            size_t base = ((size_t)(b * C5) + m) * HW + (size_t)r0 * IMW;
            if (g == 0) {
                float bv = bias[m];
                #pragma unroll
                for (int fn = 0; fn < 2; ++fn)
                    qkv[base + nwave + fn * 16 + l15] = acc[fm][fn][r] + bv;
            } else {
                #pragma unroll
                for (int fn = 0; fn < 2; ++fn)
                    qkv[base + nwave + fn * 16 + l15] += acc[fm][fn][r];
            }
        }
    }
}

// ---------- K6a: build (value || index) u64 keys for v rows ----------
__global__ void k_build_keys(const float* __restrict__ qkv, uint64_t* __restrict__ keyA) {
    int j = blockIdx.x * 256 + threadIdx.x;
    int row = blockIdx.y;               // b*64+c
    int b = row >> 6, c = row & 63;
    float v = qkv[((size_t)(b * C5) + 256 + c) * HW + j];
    keyA[(size_t)row * HW + j] = (((uint64_t)f2s(v)) << 32) | (uint32_t)j;
}

// ---------- K6b-1: per-(row,seg) 11-bit digit histogram ----------
__global__ __launch_bounds__(256) void k_rcount(const uint64_t* __restrict__ in, uint32_t* __restrict__ cntG,
                                                int shift) {
    __shared__ uint32_t hist[NBIN];
    int t = threadIdx.x;
    int seg = blockIdx.x, row = blockIdx.y;
    #pragma unroll
    for (int k = 0; k < NBIN / 256; ++k) hist[k * 256 + t] = 0;
    __syncthreads();
    const uint64_t* src = in + (size_t)row * HW + (size_t)seg * SEGN;
    #pragma unroll
    for (int i = 0; i < SEGN / 256; ++i) {
        unsigned d = (unsigned)(src[i * 256 + t] >> shift) & (NBIN - 1);
        atomicAdd(&hist[d], 1u);
    }
    __syncthreads();
    uint32_t* dstc = cntG + ((size_t)row * NSEG + seg) * NBIN;
    #pragma unroll
    for (int k = 0; k < NBIN / 256; ++k) dstc[k * 256 + t] = hist[k * 256 + t];
}

// ---------- K6b-2: per-row two-level scan -> absolute dest base per (seg,digit) ----------
__global__ __launch_bounds__(256) void k_rscan(uint32_t* __restrict__ cntG) {
    __shared__ uint32_t tot[NBIN];
    __shared__ uint32_t gsum[256];
    __shared__ uint32_t gbase[256];
    int t = threadIdx.x;
    int row = blockIdx.x;
    uint32_t* base = cntG + (size_t)row * NSEG * NBIN;
    uint32_t loc = 0;
    #pragma unroll
    for (int k = 0; k < NBIN / 256; ++k) {
        int bn = t * (NBIN / 256) + k;
        uint32_t s = 0;
        for (int sg = 0; sg < NSEG; ++sg) s += base[sg * NBIN + bn];
        tot[bn] = s;
        loc += s;
    }
    gsum[t] = loc;
    __syncthreads();
    if (t == 0) {
        uint32_t acc = 0;
        for (int i = 0; i < 256; ++i) { uint32_t v = gsum[i]; gbase[i] = acc; acc += v; }
    }
    __syncthreads();
    uint32_t run = gbase[t];
    #pragma unroll
    for (int k = 0; k < NBIN / 256; ++k) {
        int bn = t * (NBIN / 256) + k;
        uint32_t tv = tot[bn];
        uint32_t r2 = run;
        for (int sg = 0; sg < NSEG; ++sg) {
            uint32_t cv = base[sg * NBIN + bn];
            base[sg * NBIN + bn] = r2;
            r2 += cv;
        }
        run += tv;
    }
}

// ---------- K6b-3: stable scatter (11-bit): ballot rank + cross-wave prefix + running base ----------
__global__ __launch_bounds__(256) void k_rscatter(const uint64_t* __restrict__ in, uint64_t* __restrict__ out,
                                                  const uint32_t* __restrict__ cntG, int shift) {
    __shared__ uint16_t wcnt[4][NBIN];
    __shared__ uint32_t runbase[NBIN];
    int t = threadIdx.x;
    int w = t >> 6, lane = t & 63;
    int seg = blockIdx.x, row = blockIdx.y;
    const uint32_t* cbase = cntG + ((size_t)row * NSEG + seg) * NBIN;
    #pragma unroll
    for (int k = 0; k < NBIN / 256; ++k) runbase[k * 256 + t] = cbase[k * 256 + t];
    const uint64_t* src = in + (size_t)row * HW + (size_t)seg * SEGN;
    uint64_t* dst = out + (size_t)row * HW;
    for (int i = 0; i < SEGN / 256; ++i) {
        __syncthreads();
        #pragma unroll
        for (int k = 0; k < NBIN / 256; ++k)
            ((uint64_t*)wcnt)[k * 256 + t] = 0;      // zero 4*NBIN u16 = NBIN u64
        __syncthreads();
        uint64_t kv = src[i * 256 + t];
        unsigned d = (unsigned)(kv >> shift) & (NBIN - 1);
        uint64_t peers = ~0ull;
        #pragma unroll
        for (int bit = 0; bit < 11; ++bit) {
            uint64_t bm = __ballot((d >> bit) & 1u);
            peers &= ((d >> bit) & 1u) ? bm : ~bm;
        }
        unsigned lanerank = (unsigned)__popcll(peers & ((1ull << lane) - 1ull));
        unsigned wtotal = (unsigned)__popcll(peers);
        if (lanerank == 0) wcnt[w][d] = (uint16_t)wtotal;
        __syncthreads();
        unsigned wpre = 0;
        #pragma unroll
        for (int ww = 0; ww < 4; ++ww) {
            unsigned cv = wcnt[ww][d];
            if (ww < w) wpre += cv;
        }
        unsigned pos = runbase[d] + wpre + lanerank;
        dst[pos] = kv;
        __syncthreads();
        #pragma unroll
        for (int k = 0; k < NBIN / 256; ++k) {
            int bn = k * 256 + t;
            runbase[bn] += (uint32_t)wcnt[0][bn] + wcnt[1][bn] + wcnt[2][bn] + wcnt[3][bn];
        }
    }
}

// ---------- K6c: unpack sorted keys -> vs, idxv ----------
__global__ void k_unpack(const uint64_t* __restrict__ keys, float* __restrict__ vs, int* __restrict__ idxv) {
    int j = blockIdx.x * 256 + threadIdx.x;
    int row = blockIdx.y;
    size_t o = (size_t)row * HW + j;
    uint64_t k = keys[o];
    vs[o] = s2f((uint32_t)(k >> 32));
    idxv[o] = (int)(k & 0xFFFFFFFFull);
}

// ---------- K6d: gather q1,k1,q2,k2 into sorted order ----------
// v1 (known 75us): 256 blocks x 1024 thr, 1 block/CU -> blocks naturally lockstep;
// per-XCD window = 16 rows x 144KB = 2.3MB < 4MB L2 per phase.
__global__ __launch_bounds__(1024) void k_gather4(const int* __restrict__ idxv, const float* __restrict__ qkv,
                                                  float* __restrict__ g4) {
    int i = blockIdx.x;
    int row = (i & 7) * 16 + ((i >> 3) & 15);   // same-XCD blocks share a 16-row window
    int jh = i >> 7;                             // 0 or 1
    int b = row >> 6, cg = row & 63;
    const int* irow = idxv + (size_t)row * HW + jh * (HW / 2);
    size_t S4 = (size_t)BB * CC * HW;            // 4718592
    int tid = threadIdx.x;
    for (int ph = 0; ph < 4; ++ph) {
        const float* src = qkv + ((size_t)(b * C5) + ph * 64 + cg) * HW;
        float* dst = g4 + (size_t)ph * S4 + (size_t)row * HW + jh * (HW / 2);
        #pragma unroll 2
        for (int j = tid; j < HW / 2; j += 1024)
            dst[j] = src[irow[j]];
        __syncthreads();
    }
}

// ---------- K7a: S partials + norm^2 partials, streaming from g4 ----------
__global__ __launch_bounds__(256) void k_attn_qk(const float* __restrict__ g4,
                                                 float* __restrict__ partS, float* __restrict__ partN) {
    __shared__ float Qs[16][68];
    __shared__ float Ks[16][68];
    __shared__ float nqs[4][64];
    __shared__ float nks[4][64];
    int tid = threadIdx.x;
    int ychunk = blockIdx.x;   // NCHUNK chunks of CHN
    int z = blockIdx.y;        // 16 = b(2) x h(4) x variant(2)
    int vi = z & 1, hh = (z >> 1) & 3, b = z >> 3;
    size_t S4 = (size_t)BB * CC * HW;
    const float* Q = g4 + (vi ? 2 * S4 : (size_t)0);
    const float* Kp = g4 + (vi ? 3 * S4 : S4);
    int ty = tid >> 4, tx = tid & 15;
    float acc[4][4] = {};
    float nq = 0.f, nk = 0.f;
    int d0 = tid & 63, kset = tid >> 6;
    int nbase0 = ychunk * CHN;
    for (int it = 0; it < CHN / 16; ++it) {
        int nb0 = nbase0 + it * 16;
        __syncthreads();
        #pragma unroll
        for (int l = 0; l < 4; ++l) {
            int idx = l * 256 + tid;
            int d = idx >> 4, kk = idx & 15;
            int n = nb0 + kk;
            int cch = hh * 16 + (d >> 2), f = d & 3;
            size_t off = ((size_t)(b * CC) + cch) * HW + (vi ? (size_t)(n * 4 + f) : (size_t)(f * NQ + n));
            Qs[kk][d] = Q[off];
            Ks[kk][d] = Kp[off];
        }
        __syncthreads();
        #pragma unroll
        for (int kk = 0; kk < 16; ++kk) {
            float4 av = *(const float4*)&Qs[kk][ty * 4];
            float4 bv = *(const float4*)&Ks[kk][tx * 4];
            float aa[4] = {av.x, av.y, av.z, av.w};
            float bb[4] = {bv.x, bv.y, bv.z, bv.w};
            #pragma unroll
            for (int i = 0; i < 4; ++i)
                #pragma unroll
                for (int j = 0; j < 4; ++j)
                    acc[i][j] = fmaf(aa[i], bb[j], acc[i][j]);
        }
        #pragma unroll
        for (int kk2 = 0; kk2 < 4; ++kk2) {
            float qv = Qs[kset * 4 + kk2][d0];
            float kv = Ks[kset * 4 + kk2][d0];
            nq = fmaf(qv, qv, nq);
            nk = fmaf(kv, kv, nk);
        }
    }
    size_t sb = ((size_t)z * NCHUNK + ychunk) * 4096;
    #pragma unroll
    for (int i = 0; i < 4; ++i)
        #pragma unroll
        for (int j = 0; j < 4; ++j)
            partS[sb + (size_t)(ty * 4 + i) * 64 + tx * 4 + j] = acc[i][j];
    nqs[kset][d0] = nq;
    nks[kset][d0] = nk;
    __syncthreads();
    if (tid < 64) {
        float sq = nqs[0][tid] + nqs[1][tid] + nqs[2][tid] + nqs[3][tid];
        float sk = nks[0][tid] + nks[1][tid] + nks[2][tid] + nks[3][tid];
        size_t nb2 = ((size_t)z * NCHUNK + ychunk) * 128;
        partN[nb2 + tid] = sq;
        partN[nb2 + 64 + tid] = sk;
    }
}

// ---------- K7b: reduce partials, normalize, exp, denom = rowsum+1 ; write attn^T ----------
__global__ __launch_bounds__(256) void k_attn_softmax(const float* __restrict__ partS,
                                                      const float* __restrict__ partN,
                                                      const float* __restrict__ temp, float* __restrict__ attnT) {
    __shared__ float nqv[64], nkv[64];
    __shared__ float pbuf[64][65];
    __shared__ float rred[64][4];
    __shared__ float rsum[64];
    int tid = threadIdx.x;
    int z = blockIdx.x;
    int hh = (z >> 1) & 3;
    if (tid < 128) {
        float s = 0.f;
        for (int ch = 0; ch < NCHUNK; ++ch) s += partN[((size_t)z * NCHUNK + ch) * 128 + tid];
        float nv = fmaxf(sqrtf(s), 1e-12f);
        if (tid < 64) nqv[tid] = nv; else nkv[tid - 64] = nv;
    }
    __syncthreads();
    float tf = temp[hh];
    int d = tid >> 2, qq = tid & 3;
    float psum = 0.f;
    for (int e = qq * 16; e < qq * 16 + 16; ++e) {
        float s = 0.f;
        for (int ch = 0; ch < NCHUNK; ++ch) s += partS[((size_t)z * NCHUNK + ch) * 4096 + (size_t)d * 64 + e];
        float p = expf(tf * s / (nqv[d] * nkv[e]));
        pbuf[d][e] = p;
        psum += p;
    }
    rred[d][qq] = psum;
    __syncthreads();
    if (tid < 64) rsum[tid] = rred[tid][0] + rred[tid][1] + rred[tid][2] + rred[tid][3] + 1.0f;
    __syncthreads();
    for (int e = qq * 16; e < qq * 16 + 16; ++e)
        attnT[(size_t)z * 4096 + (size_t)e * 64 + d] = pbuf[d][e] / rsum[d];
}

// ---------- K7c: O = attn * V, written back to (c, sorted-position) layout ----------
__global__ __launch_bounds__(256) void k_attn_av(const float* __restrict__ attnT, const float* __restrict__ vs,
                                                 float* __restrict__ O1, float* __restrict__ O2) {
    __shared__ float at_s[4096];
    int tid = threadIdx.x;
    int z = blockIdx.y;
    int vi = z & 1, hh = (z >> 1) & 3, b = z >> 3;
    for (int l = 0; l < 16; ++l) at_s[l * 256 + tid] = attnT[(size_t)z * 4096 + l * 256 + tid];
    __syncthreads();
    int n = blockIdx.x * 256 + tid;
    float acc[64];
    #pragma unroll
    for (int d = 0; d < 64; ++d) acc[d] = 0.f;
    for (int e = 0; e < 64; ++e) {
        int cch = hh * 16 + (e >> 2), f = e & 3;
        size_t p = vi ? (size_t)(n * 4 + f) : (size_t)(f * NQ + n);
        float vv = vs[((size_t)(b * CC) + cch) * HW + p];
        const float* ar = &at_s[e * 64];
        #pragma unroll
        for (int d4 = 0; d4 < 16; ++d4) {
            float4 a4 = *(const float4*)&ar[d4 * 4];
            acc[d4 * 4 + 0] = fmaf(a4.x, vv, acc[d4 * 4 + 0]);
            acc[d4 * 4 + 1] = fmaf(a4.y, vv, acc[d4 * 4 + 1]);
            acc[d4 * 4 + 2] = fmaf(a4.z, vv, acc[d4 * 4 + 2]);
            acc[d4 * 4 + 3] = fmaf(a4.w, vv, acc[d4 * 4 + 3]);
        }
    }
    float* Ob = vi ? O2 : O1;
    #pragma unroll
    for (int d = 0; d < 64; ++d) {
        int cch = hh * 16 + (d >> 2), f = d & 3;
        size_t p = vi ? (size_t)(n * 4 + f) : (size_t)(f * NQ + n);
        Ob[((size_t)(b * CC) + cch) * HW + p] = acc[d];
    }
}

// ---------- K8: product in sorted domain, scatter to original positions via idxv ----------
__global__ void k_prod_scatter(const float* __restrict__ O1, const float* __restrict__ O2,
                               const int* __restrict__ idxv, float* __restrict__ pu) {
    int j = blockIdx.x * 256 + threadIdx.x;
    int row = blockIdx.y;
    size_t o = (size_t)row * HW + j;
    int p = idxv[o];
    pu[(size_t)row * HW + p] = O1[o] * O2[o];
}

// ---------- K9: proj GEMM 64x64 ----------
__global__ __launch_bounds__(256) void k_gemm_proj(const float* __restrict__ wp, const float* __restrict__ pu,
                                                   float* __restrict__ op) {
    __shared__ float wt[4096];  // wt[c*64+m] = wp[m*64+c]
    int tid = threadIdx.x;
    for (int l = 0; l < 16; ++l) {
        int i = l * 256 + tid;
        int m = i >> 6, c = i & 63;
        wt[c * 64 + m] = wp[i];
    }
    __syncthreads();
    int b = blockIdx.y;
    int n = blockIdx.x * 256 + tid;
    float acc[64];
    #pragma unroll
    for (int m = 0; m < 64; ++m) acc[m] = 0.f;
    const float* src = pu + (size_t)(b * CC) * HW + n;
    for (int c = 0; c < 64; ++c) {
        float xv = src[(size_t)c * HW];
        const float* wr = &wt[c * 64];
        #pragma unroll
        for (int m4 = 0; m4 < 16; ++m4) {
            float4 w4 = *(const float4*)&wr[m4 * 4];
            acc[m4 * 4 + 0] = fmaf(w4.x, xv, acc[m4 * 4 + 0]);
            acc[m4 * 4 + 1] = fmaf(w4.y, xv, acc[m4 * 4 + 1]);
            acc[m4 * 4 + 2] = fmaf(w4.z, xv, acc[m4 * 4 + 2]);
            acc[m4 * 4 + 3] = fmaf(w4.w, xv, acc[m4 * 4 + 3]);
        }
    }
    float* dst = op + (size_t)(b * CC) * HW + n;
    for (int m = 0; m < 64; ++m) dst[(size_t)m * HW] = acc[m];
}

// ---------- K10: spatial unsort scatter for c<32, copy c>=32 ----------
__global__ void k_final(const float* __restrict__ op, const int* __restrict__ idx_h,
                        const int* __restrict__ idx_w, float* __restrict__ out) {
    int i = blockIdx.x * 256 + threadIdx.x;
    int p = i % HW;
    int c = (i / HW) % CC;
    int b = i / (HW * CC);
    float v = op[i];
    if (c < CHF) {
        int h = p / IMW, w = p % IMW;
        size_t ib = ((size_t)(b * CHF) + c) * HW;
        int W0 = idx_w[ib + h * IMW + w];
        int H0 = idx_h[ib + h * IMW + W0];
        out[((size_t)(b * CC) + c) * HW + H0 * IMW + W0] = v;
    } else {
        out[i] = v;
    }
}

extern "C" void kernel_launch(void* const* d_in, const int* in_sizes, int n_in,
                              void* d_out, int out_size, void* d_ws, size_t ws_size,
                              hipStream_t stream) {
    (void)in_sizes; (void)n_in; (void)out_size; (void)ws_size;
    const float* x    = (const float*)d_in[0];
    const float* temp = (const float*)d_in[1];
    const float* wq   = (const float*)d_in[2];
    const float* wd3  = (const float*)d_in[3];
    const float* wd5  = (const float*)d_in[4];
    const float* wd7  = (const float*)d_in[5];
    const float* wf   = (const float*)d_in[6];
    const float* bf   = (const float*)d_in[7];
    const float* wp   = (const float*)d_in[8];
    float* out = (float*)d_out;
    float* ws = (float*)d_ws;

    // ---- workspace arena: peak 59,768,832 floats (~228 MiB) ----
    int*      idx_h = (int*)(ws + 0);
    int*      idx_w = (int*)(ws + 2359296);
    float*    A     = ws + 4718592;
    float*    slice = ws + 4718592;                    // over dead A
    float*    q     = ws + 12582912;
    float*    qkv   = ws + 36175872;
    uint64_t* keyA  = (uint64_t*)(ws + 12582912);      // over dead q
    uint64_t* keyB  = (uint64_t*)(ws + 22020096);
    float*    vs    = ws + 31457280;
    uint32_t* cntG  = (uint32_t*)(ws + 4718592);       // 128*16*2048 u32 (over dead slice)
    int*      idxv  = (int*)(ws + 4718592);            // after radix (over dead cntG)
    float*    g4    = ws + 12582912;                   // over dead keyA+keyB
    float*    O1    = ws + 36175872;                   // over dead qkv
    float*    O2    = ws + 40894464;
    float*    pu    = ws + 45613056;
    float*    op    = ws + 50331648;                   // ends 55050240
    float*    partS = ws + 55050240;                   // 2097152
    float*    partN = ws + 57147392;                   // 65536
    float*    attnT = ws + 57212928;                   // 65536 -> ends 57278464

    k_copy_back<<<9216, 256, 0, stream>>>(x, A);
    k_sort_h<<<12288, 128, 0, stream>>>(x, A, idx_h);
    k_sort_w<<<12288, 128, 0, stream>>>(A, idx_w);
    k_gemm_q<<<dim3(576, 5, 2), 256, 0, stream>>>(wq, A, q);

    for (int g = 0; g < 3; ++g) {
        for (int chunk = 0; chunk < 3; ++chunk) {
            int r0 = chunk * CROWS;
            if (g == 0)      k_dwconv<3><<<dim3(12, 320, 2), 256, 0, stream>>>(q, wd3, slice, r0);
            else if (g == 1) k_dwconv<5><<<dim3(12, 320, 2), 256, 0, stream>>>(q, wd5, slice, r0);
            else             k_dwconv<7><<<dim3(12, 320, 2), 256, 0, stream>>>(q, wd7, slice, r0);
            k_gemm_fuse<<<dim3(96, 5, 2), 256, 0, stream>>>(wf, slice, bf, qkv, g, r0);
        }
    }

    k_build_keys<<<dim3(144, 128), 256, 0, stream>>>(qkv, keyA);
    // 3 stable LSD passes of 11 bits over the value (bits 32..63); final result in keyB
    const int shifts[3] = {32, 43, 54};
    for (int p = 0; p < 3; ++p) {
        const uint64_t* src = (p & 1) ? keyB : keyA;
        uint64_t*       dst = (p & 1) ? keyA : keyB;
        k_rcount  <<<dim3(NSEG, 128), 256, 0, stream>>>(src, cntG, shifts[p]);
        k_rscan   <<<128, 256, 0, stream>>>(cntG);
        k_rscatter<<<dim3(NSEG, 128), 256, 0, stream>>>(src, dst, cntG, shifts[p]);
    }
    k_unpack<<<dim3(144, 128), 256, 0, stream>>>(keyB, vs, idxv);
    k_gather4<<<256, 1024, 0, stream>>>(idxv, qkv, g4);

    k_attn_qk<<<dim3(NCHUNK, 16), 256, 0, stream>>>(g4, partS, partN);
    k_attn_softmax<<<16, 256, 0, stream>>>(partS, partN, temp, attnT);
    k_attn_av<<<dim3(36, 16), 256, 0, stream>>>(attnT, vs, O1, O2);

    k_prod_scatter<<<dim3(144, 128), 256, 0, stream>>>(O1, O2, idxv, pu);
    k_gemm_proj<<<dim3(144, 2), 256, 0, stream>>>(wp, pu, op);
    k_final<<<18432, 256, 0, stream>>>(op, idx_h, idx_w, out);
}

// Round 7
// 1216.646 us; speedup vs baseline: 1.3559x; 1.0156x over previous
//
#include <hip/hip_runtime.h>
#include <stdint.h>
#include <stddef.h>

constexpr int IMH = 192;
constexpr int IMW = 192;
constexpr int HW  = 36864;   // 192*192
constexpr int BB  = 2;
constexpr int CC  = 64;
constexpr int CHF = 32;      // half channels (sorted part)
constexpr int C5  = 320;     // 5*CC
constexpr int NQ  = 9216;    // HW/4
constexpr int CROWS = 64;    // fuse-pipeline chunk rows
constexpr int CHWN  = CROWS * IMW;  // 12288 cols per chunk
constexpr int NCHUNK = 32;   // attn_qk n-chunks per z
constexpr int CHN = HW / 4 / NCHUNK;  // 288 n per chunk
constexpr int NSEG = 12;     // radix segments per row (12 -> cntG fits the free hole exactly)
constexpr int SEGN = HW / NSEG;      // 3072 elements per segment (= 12 * 256)
constexpr int NBIN = 2048;   // 11-bit radix

typedef float fx2 __attribute__((ext_vector_type(2)));
typedef float fx4 __attribute__((ext_vector_type(4)));
typedef _Float16 f16;
typedef _Float16 f16x8 __attribute__((ext_vector_type(8)));
typedef float f32x4 __attribute__((ext_vector_type(4)));

// ---------- float <-> monotone uint32 (order-preserving, invertible) ----------
static __device__ __forceinline__ uint32_t f2s(float f) {
    uint32_t u = __float_as_uint(f);
    return (u & 0x80000000u) ? ~u : (u | 0x80000000u);
}
static __device__ __forceinline__ float s2f(uint32_t s) {
    uint32_t u = (s & 0x80000000u) ? (s & 0x7FFFFFFFu) : ~s;
    return __uint_as_float(u);
}

// ---------- bitonic sort of 256 u64 keys in LDS (128 threads) ----------
static __device__ void bitonic256(uint64_t* keys, int tid) {
    for (unsigned k = 2; k <= 256; k <<= 1) {
        for (unsigned j = k >> 1; j; j >>= 1) {
            __syncthreads();
            unsigned i = ((tid & ~(j - 1)) << 1) | (tid & (j - 1));
            unsigned p = i | j;
            bool up = ((i & k) == 0);
            uint64_t a = keys[i], b = keys[p];
            if ((a > b) == up) { keys[i] = b; keys[p] = a; }
        }
    }
    __syncthreads();
}

// ---------- K1: stable sort along H (per b,c,w column), write A + idx_h ----------
__global__ __launch_bounds__(128) void k_sort_h(const float* __restrict__ x, float* __restrict__ A,
                                                int* __restrict__ idx_h) {
    __shared__ uint64_t keys[256];
    int tid = threadIdx.x;
    int blk = blockIdx.x;
    int w = blk % IMW;
    int c = (blk / IMW) % CHF;
    int b = blk / (IMW * CHF);
    const float* col = x + ((size_t)(b * CC) + c) * HW + w;
    for (int i = tid; i < 256; i += 128)
        keys[i] = (i < IMH) ? ((((uint64_t)f2s(col[(size_t)i * IMW])) << 32) | (uint32_t)i) : ~0ull;
    bitonic256(keys, tid);
    float* ocol = A + ((size_t)(b * CC) + c) * HW + w;
    int* icol = idx_h + ((size_t)(b * CHF) + c) * HW + w;
    for (int i = tid; i < IMH; i += 128) {
        uint64_t k = keys[i];
        ocol[(size_t)i * IMW] = s2f((uint32_t)(k >> 32));
        icol[(size_t)i * IMW] = (int)(k & 0xFFFFFFFFull);
    }
}

// ---------- K2: stable sort along W (per b,c,h row), in-place on A, write idx_w ----------
__global__ __launch_bounds__(128) void k_sort_w(float* __restrict__ A, int* __restrict__ idx_w) {
    __shared__ uint64_t keys[256];
    int tid = threadIdx.x;
    int blk = blockIdx.x;
    int h = blk % IMH;
    int c = (blk / IMH) % CHF;
    int b = blk / (IMH * CHF);
    float* row = A + ((size_t)(b * CC) + c) * HW + (size_t)h * IMW;
    for (int i = tid; i < 256; i += 128)
        keys[i] = (i < IMW) ? ((((uint64_t)f2s(row[i])) << 32) | (uint32_t)i) : ~0ull;
    bitonic256(keys, tid);
    int* irow = idx_w + ((size_t)(b * CHF) + c) * HW + (size_t)h * IMW;
    for (int i = tid; i < IMW; i += 128) {
        uint64_t k = keys[i];
        row[i] = s2f((uint32_t)(k >> 32));
        irow[i] = (int)(k & 0xFFFFFFFFull);
    }
}

// ---------- K3: q = W_qkv(320x64) * A(64xHW) per batch ----------
// v2: reads sorted half (c<32) from A, unsorted half (c>=32) straight from x.
__global__ __launch_bounds__(256) void k_gemm_q(const float* __restrict__ wq, const float* __restrict__ A,
                                                const float* __restrict__ x, float* __restrict__ q) {
    __shared__ float Wt[64][68];
    __shared__ float Xt[64][68];
    int tid = threadIdx.x;
    int n0 = blockIdx.x * 64, m0 = blockIdx.y * 64, b = blockIdx.z;
    for (int l = 0; l < 16; ++l) {
        int idx = l * 256 + tid;
        int cc = idx & 63, m = idx >> 6;
        Wt[cc][m] = wq[(size_t)(m0 + m) * 64 + cc];
    }
    for (int l = 0; l < 16; ++l) {
        int idx = l * 256 + tid;
        int n = idx & 63, cc = idx >> 6;
        const float* sp = (cc < CHF) ? A : x;
        Xt[cc][n] = sp[((size_t)(b * CC) + cc) * HW + n0 + n];
    }
    __syncthreads();
    int ty = tid >> 4, tx = tid & 15;
    float acc[4][4] = {};
    for (int cc = 0; cc < 64; ++cc) {
        float4 av = *(const float4*)&Wt[cc][ty * 4];
        float4 bv = *(const float4*)&Xt[cc][tx * 4];
        float aa[4] = {av.x, av.y, av.z, av.w};
        float bb[4] = {bv.x, bv.y, bv.z, bv.w};
        #pragma unroll
        for (int i = 0; i < 4; ++i)
            #pragma unroll
            for (int j = 0; j < 4; ++j)
                acc[i][j] = fmaf(aa[i], bb[j], acc[i][j]);
    }
    for (int i = 0; i < 4; ++i) {
        float4 o;
        o.x = acc[i][0]; o.y = acc[i][1]; o.z = acc[i][2]; o.w = acc[i][3];
        *(float4*)&q[((size_t)(b * C5) + m0 + ty * 4 + i) * HW + n0 + tx * 4] = o;
    }
}

// ---------- K4: depthwise conv KSxKS (zero pad) for a 64-row chunk starting at r0 ----------
template <int KS>
__global__ __launch_bounds__(256) void k_dwconv(const float* __restrict__ q, const float* __restrict__ wd,
                                                float* __restrict__ slice, int r0) {
    constexpr int PAD = KS / 2;
    constexpr int EXT = 32 + 2 * PAD;
    __shared__ float tile[EXT][EXT];
    int tid = threadIdx.x;
    int b = blockIdx.z, c = blockIdx.y;
    int t = blockIdx.x;                  // 12 tiles: 2 tile-rows x 6 tile-cols
    int ty0 = r0 + (t / 6) * 32, tx0 = (t % 6) * 32;
    const float* src = q + ((size_t)(b * C5) + c) * HW;
    for (int i = tid; i < EXT * EXT; i += 256) {
        int iy = i / EXT, ix = i % EXT;
        int gy = ty0 + iy - PAD, gx = tx0 + ix - PAD;
        float v = 0.f;
        if (gy >= 0 && gy < IMH && gx >= 0 && gx < IMW) v = src[gy * IMW + gx];
        tile[iy][ix] = v;
    }
    __syncthreads();
    float wreg[KS * KS];
    #pragma unroll
    for (int i = 0; i < KS * KS; ++i) wreg[i] = wd[(size_t)c * KS * KS + i];
    float* dst = slice + ((size_t)(b * C5) + c) * CHWN;
    #pragma unroll
    for (int k = 0; k < 4; ++k) {
        int pix = k * 256 + tid;
        int py = pix >> 5, px = pix & 31;
        float acc = 0.f;
        #pragma unroll
        for (int ky = 0; ky < KS; ++ky)
            #pragma unroll
            for (int kx = 0; kx < KS; ++kx)
                acc = fmaf(tile[py + ky][px + kx], wreg[ky * KS + kx], acc);
        dst[(ty0 - r0 + py) * IMW + tx0 + px] = acc;
    }
}

// ---------- K5: qkv(chunk) (+)= W_fuse[:, g*320:(g+1)*320] * slice(chunk) ----------
// v5 (MFMA f16x2, in-kernel W split): C = Wh*Xh + Wh*Xl + Wl*Xh via
// mfma_f32_16x16x32_f16 (neglected Wl*Xl term ~2^-22 rel; fp32-equivalent at K=960).
// C/D layout (m89-verified): col=lane&15 -> n, row=4*(lane>>4)+reg -> m.
__global__ __launch_bounds__(256) void k_gemm_fuse(const float* __restrict__ wf,
                                                   const float* __restrict__ slice, const float* __restrict__ bias,
                                                   float* __restrict__ qkv, int g, int r0) {
    __shared__ f16 Ah[64][40];
    __shared__ f16 Al[64][40];
    int tid = threadIdx.x;
    int n0 = blockIdx.x * 128, m0 = blockIdx.y * 64, b = blockIdx.z;
    int lane = tid & 63, wv = tid >> 6;
    int l15 = lane & 15, lg = lane >> 4;
    int nwave = n0 + wv * 32;                 // wave's 32-col n-strip
    int sm = tid >> 2, skr = (tid & 3) * 8;   // W staging: m=tid>>2, 8 consecutive k
    int gk = g * 320;
    f32x4 acc[4][2];
    #pragma unroll
    for (int i = 0; i < 4; ++i)
        #pragma unroll
        for (int j = 0; j < 2; ++j)
            acc[i][j] = (f32x4){0.f, 0.f, 0.f, 0.f};

    const float* xcol = slice + (size_t)(b * C5) * CHWN + nwave + l15;
    const float* wrow = wf + (size_t)(m0 + sm) * 960 + gk + skr;

    for (int k0 = 0; k0 < 320; k0 += 32) {
        if (k0) __syncthreads();
        // stage W tile: fp32 -> f16 hi/lo split in registers -> LDS
        {
            float4 w0 = *(const float4*)(wrow + k0);
            float4 w1 = *(const float4*)(wrow + k0 + 4);
            float wvv[8] = {w0.x, w0.y, w0.z, w0.w, w1.x, w1.y, w1.z, w1.w};
            f16x8 hv, lv;
            #pragma unroll
            for (int j = 0; j < 8; ++j) {
                f16 h = (f16)wvv[j];
                hv[j] = h;
                lv[j] = (f16)(wvv[j] - (float)h);
            }
            *(f16x8*)&Ah[sm][skr] = hv;
            *(f16x8*)&Al[sm][skr] = lv;
        }
        float xv[2][8];
        #pragma unroll
        for (int fn = 0; fn < 2; ++fn)
            #pragma unroll
            for (int j = 0; j < 8; ++j)
                xv[fn][j] = xcol[(size_t)(k0 + lg * 8 + j) * CHWN + fn * 16];
        __syncthreads();
        f16x8 bh[2], bl[2];
        #pragma unroll
        for (int fn = 0; fn < 2; ++fn)
            #pragma unroll
            for (int j = 0; j < 8; ++j) {
                float v = xv[fn][j];
                f16 h = (f16)v;
                bh[fn][j] = h;
                bl[fn][j] = (f16)(v - (float)h);
            }
        #pragma unroll
        for (int fm = 0; fm < 4; ++fm) {
            f16x8 ah = *(const f16x8*)&Ah[fm * 16 + l15][lg * 8];
            f16x8 al = *(const f16x8*)&Al[fm * 16 + l15][lg * 8];
            #pragma unroll
            for (int fn = 0; fn < 2; ++fn) {
                acc[fm][fn] = __builtin_amdgcn_mfma_f32_16x16x32_f16(ah, bh[fn], acc[fm][fn], 0, 0, 0);
                acc[fm][fn] = __builtin_amdgcn_mfma_f32_16x16x32_f16(ah, bl[fn], acc[fm][fn], 0, 0, 0);
                acc[fm][fn] = __builtin_amdgcn_mfma_f32_16x16x32_f16(al, bh[fn], acc[fm][fn], 0, 0, 0);
            }
        }
    }

    #pragma unroll
    for (int fm = 0; fm < 4; ++fm) {
        #pragma unroll
        for (int r = 0; r < 4; ++r) {
            int m = m0 + fm * 16 + lg * 4 + r;
            size_t base = ((size_t)(b * C5) + m) * HW + (size_t)r0 * IMW;
            if (g == 0) {
                float bv = bias[m];
                #pragma unroll
                for (int fn = 0; fn < 2; ++fn)
                    qkv[base + nwave + fn * 16 + l15] = acc[fm][fn][r] + bv;
            } else {
                #pragma unroll
                for (int fn = 0; fn < 2; ++fn)
                    qkv[base + nwave + fn * 16 + l15] += acc[fm][fn][r];
            }
        }
    }
}

// ---------- K6b-1: per-(row,seg) 11-bit digit histogram ----------
// FIRST=1: read qkv v-plane directly (key formed on the fly, shift==32).
template <int FIRST>
__global__ __launch_bounds__(256) void k_rcount(const uint64_t* __restrict__ in, const float* __restrict__ qkvv,
                                                uint32_t* __restrict__ cntG, int shift) {
    __shared__ uint32_t hist[NBIN];
    int t = threadIdx.x;
    int seg = blockIdx.x, row = blockIdx.y;
    #pragma unroll
    for (int k = 0; k < NBIN / 256; ++k) hist[k * 256 + t] = 0;
    __syncthreads();
    if (FIRST) {
        int bb = row >> 6, c = row & 63;
        const float* srcf = qkvv + ((size_t)(bb * C5) + 256 + c) * HW + (size_t)seg * SEGN;
        #pragma unroll
        for (int i = 0; i < SEGN / 256; ++i) {
            unsigned d = f2s(srcf[i * 256 + t]) & (NBIN - 1);   // shift==32
            atomicAdd(&hist[d], 1u);
        }
    } else {
        const uint64_t* src = in + (size_t)row * HW + (size_t)seg * SEGN;
        #pragma unroll
        for (int i = 0; i < SEGN / 256; ++i) {
            unsigned d = (unsigned)(src[i * 256 + t] >> shift) & (NBIN - 1);
            atomicAdd(&hist[d], 1u);
        }
    }
    __syncthreads();
    uint32_t* dstc = cntG + ((size_t)row * NSEG + seg) * NBIN;
    #pragma unroll
    for (int k = 0; k < NBIN / 256; ++k) dstc[k * 256 + t] = hist[k * 256 + t];
}

// ---------- K6b-2: per-row two-level scan -> absolute dest base per (seg,digit) ----------
__global__ __launch_bounds__(256) void k_rscan(uint32_t* __restrict__ cntG) {
    __shared__ uint32_t tot[NBIN];
    __shared__ uint32_t gsum[256];
    __shared__ uint32_t gbase[256];
    int t = threadIdx.x;
    int row = blockIdx.x;
    uint32_t* base = cntG + (size_t)row * NSEG * NBIN;
    uint32_t loc = 0;
    #pragma unroll
    for (int k = 0; k < NBIN / 256; ++k) {
        int bn = t * (NBIN / 256) + k;
        uint32_t s = 0;
        for (int sg = 0; sg < NSEG; ++sg) s += base[sg * NBIN + bn];
        tot[bn] = s;
        loc += s;
    }
    gsum[t] = loc;
    __syncthreads();
    if (t == 0) {
        uint32_t acc = 0;
        for (int i = 0; i < 256; ++i) { uint32_t v = gsum[i]; gbase[i] = acc; acc += v; }
    }
    __syncthreads();
    uint32_t run = gbase[t];
    #pragma unroll
    for (int k = 0; k < NBIN / 256; ++k) {
        int bn = t * (NBIN / 256) + k;
        uint32_t tv = tot[bn];
        uint32_t r2 = run;
        for (int sg = 0; sg < NSEG; ++sg) {
            uint32_t cv = base[sg * NBIN + bn];
            base[sg * NBIN + bn] = r2;
            r2 += cv;
        }
        run += tv;
    }
}

// ---------- K6b-3: stable scatter (11-bit): ballot rank + cross-wave prefix + running base ----------
// MODE 0: key->key. MODE 1: qkv->key (first pass, key formed on the fly, shift==32).
// MODE 2: key->vs+idxv (last pass, unpack fused; same 8B/elt written).
template <int MODE>
__global__ __launch_bounds__(256) void k_rscatter(const uint64_t* __restrict__ in, const float* __restrict__ qkvv,
                                                  uint64_t* __restrict__ out, float* __restrict__ vso,
                                                  int* __restrict__ idxo, const uint32_t* __restrict__ cntG,
                                                  int shift) {
    __shared__ uint16_t wcnt[4][NBIN];
    __shared__ uint32_t runbase[NBIN];
    int t = threadIdx.x;
    int w = t >> 6, lane = t & 63;
    int seg = blockIdx.x, row = blockIdx.y;
    const uint32_t* cbase = cntG + ((size_t)row * NSEG + seg) * NBIN;
    #pragma unroll
    for (int k = 0; k < NBIN / 256; ++k) runbase[k * 256 + t] = cbase[k * 256 + t];
    for (int i = 0; i < SEGN / 256; ++i) {
        __syncthreads();
        #pragma unroll
        for (int k = 0; k < NBIN / 256; ++k)
            ((uint64_t*)wcnt)[k * 256 + t] = 0;      // zero 4*NBIN u16 = NBIN u64
        __syncthreads();
        uint64_t kv;
        if (MODE == 1) {
            int bb = row >> 6, c = row & 63;
            const float* srcf = qkvv + ((size_t)(bb * C5) + 256 + c) * HW + (size_t)seg * SEGN;
            kv = (((uint64_t)f2s(srcf[i * 256 + t])) << 32) | (uint32_t)(seg * SEGN + i * 256 + t);
        } else {
            const uint64_t* src = in + (size_t)row * HW + (size_t)seg * SEGN;
            kv = src[i * 256 + t];
        }
        unsigned d = (unsigned)(kv >> shift) & (NBIN - 1);
        uint64_t peers = ~0ull;
        #pragma unroll
        for (int bit = 0; bit < 11; ++bit) {
            uint64_t bm = __ballot((d >> bit) & 1u);
            peers &= ((d >> bit) & 1u) ? bm : ~bm;
        }
        unsigned lanerank = (unsigned)__popcll(peers & ((1ull << lane) - 1ull));
        unsigned wtotal = (unsigned)__popcll(peers);
        if (lanerank == 0) wcnt[w][d] = (uint16_t)wtotal;
        __syncthreads();
        unsigned wpre = 0;
        #pragma unroll
        for (int ww = 0; ww < 4; ++ww) {
            unsigned cv = wcnt[ww][d];
            if (ww < w) wpre += cv;
        }
        unsigned pos = runbase[d] + wpre + lanerank;
        if (MODE == 2) {
            vso[(size_t)row * HW + pos] = s2f((uint32_t)(kv >> 32));
            idxo[(size_t)row * HW + pos] = (int)(kv & 0xFFFFFFFFull);
        } else {
            out[(size_t)row * HW + pos] = kv;
        }
        __syncthreads();
        #pragma unroll
        for (int k = 0; k < NBIN / 256; ++k) {
            int bn = k * 256 + t;
            runbase[bn] += (uint32_t)wcnt[0][bn] + wcnt[1][bn] + wcnt[2][bn] + wcnt[3][bn];
        }
    }
}

// ---------- K6d: gather q1,k1,q2,k2 into sorted order ----------
// v4: v1's 1-block/CU phase-lockstep structure (known-good 2.3MB L2 window) + idx
// preloaded ONCE into registers (9 x int2/thread), 2-wide gathers, nontemporal
// streaming stores (output never re-read from L2).
__global__ __launch_bounds__(1024) void k_gather4(const int* __restrict__ idxv, const float* __restrict__ qkv,
                                                  float* __restrict__ g4) {
    int i = blockIdx.x;
    int row = (i & 7) * 16 + ((i >> 3) & 15);   // same-XCD blocks share a 16-row window
    int jh = i >> 7;                             // 0 or 1
    int b = row >> 6, cg = row & 63;
    const int* irow = idxv + (size_t)row * HW + jh * (HW / 2);
    size_t S4 = (size_t)BB * CC * HW;            // 4718592
    int tid = threadIdx.x;
    int2 pidx[9];
    #pragma unroll
    for (int s = 0; s < 9; ++s)
        pidx[s] = *(const int2*)&irow[s * 2048 + tid * 2];
    for (int ph = 0; ph < 4; ++ph) {
        const float* src = qkv + ((size_t)(b * C5) + ph * 64 + cg) * HW;
        float* dst = g4 + (size_t)ph * S4 + (size_t)row * HW + jh * (HW / 2);
        #pragma unroll 3
        for (int s = 0; s < 9; ++s) {
            fx2 v;
            v.x = src[pidx[s].x];
            v.y = src[pidx[s].y];
            __builtin_nontemporal_store(v, (fx2*)&dst[s * 2048 + tid * 2]);
        }
        __syncthreads();                         // keep all waves in the same phase
    }
}

// ---------- K7a: S partials + norm^2 partials, streaming from g4 ----------
__global__ __launch_bounds__(256) void k_attn_qk(const float* __restrict__ g4,
                                                 float* __restrict__ partS, float* __restrict__ partN) {
    __shared__ float Qs[16][68];
    __shared__ float Ks[16][68];
    __shared__ float nqs[4][64];
    __shared__ float nks[4][64];
    int tid = threadIdx.x;
    int ychunk = blockIdx.x;   // NCHUNK chunks of CHN
    int z = blockIdx.y;        // 16 = b(2) x h(4) x variant(2)
    int vi = z & 1, hh = (z >> 1) & 3, b = z >> 3;
    size_t S4 = (size_t)BB * CC * HW;
    const float* Q = g4 + (vi ? 2 * S4 : (size_t)0);
    const float* Kp = g4 + (vi ? 3 * S4 : S4);
    int ty = tid >> 4, tx = tid & 15;
    float acc[4][4] = {};
    float nq = 0.f, nk = 0.f;
    int d0 = tid & 63, kset = tid >> 6;
    int nbase0 = ychunk * CHN;
    for (int it = 0; it < CHN / 16; ++it) {
        int nb0 = nbase0 + it * 16;
        __syncthreads();
        #pragma unroll
        for (int l = 0; l < 4; ++l) {
            int idx = l * 256 + tid;
            int d = idx >> 4, kk = idx & 15;
            int n = nb0 + kk;
            int cch = hh * 16 + (d >> 2), f = d & 3;
            size_t off = ((size_t)(b * CC) + cch) * HW + (vi ? (size_t)(n * 4 + f) : (size_t)(f * NQ + n));
            Qs[kk][d] = Q[off];
            Ks[kk][d] = Kp[off];
        }
        __syncthreads();
        #pragma unroll
        for (int kk = 0; kk < 16; ++kk) {
            float4 av = *(const float4*)&Qs[kk][ty * 4];
            float4 bv = *(const float4*)&Ks[kk][tx * 4];
            float aa[4] = {av.x, av.y, av.z, av.w};
            float bb[4] = {bv.x, bv.y, bv.z, bv.w};
            #pragma unroll
            for (int i = 0; i < 4; ++i)
                #pragma unroll
                for (int j = 0; j < 4; ++j)
                    acc[i][j] = fmaf(aa[i], bb[j], acc[i][j]);
        }
        #pragma unroll
        for (int kk2 = 0; kk2 < 4; ++kk2) {
            float qv = Qs[kset * 4 + kk2][d0];
            float kv = Ks[kset * 4 + kk2][d0];
            nq = fmaf(qv, qv, nq);
            nk = fmaf(kv, kv, nk);
        }
    }
    size_t sb = ((size_t)z * NCHUNK + ychunk) * 4096;
    #pragma unroll
    for (int i = 0; i < 4; ++i)
        #pragma unroll
        for (int j = 0; j < 4; ++j)
            partS[sb + (size_t)(ty * 4 + i) * 64 + tx * 4 + j] = acc[i][j];
    nqs[kset][d0] = nq;
    nks[kset][d0] = nk;
    __syncthreads();
    if (tid < 64) {
        float sq = nqs[0][tid] + nqs[1][tid] + nqs[2][tid] + nqs[3][tid];
        float sk = nks[0][tid] + nks[1][tid] + nks[2][tid] + nks[3][tid];
        size_t nb2 = ((size_t)z * NCHUNK + ychunk) * 128;
        partN[nb2 + tid] = sq;
        partN[nb2 + 64 + tid] = sk;
    }
}

// ---------- K7b: reduce partials, normalize, exp, denom = rowsum+1 ; write attn^T ----------
__global__ __launch_bounds__(256) void k_attn_softmax(const float* __restrict__ partS,
                                                      const float* __restrict__ partN,
                                                      const float* __restrict__ temp, float* __restrict__ attnT) {
    __shared__ float nqv[64], nkv[64];
    __shared__ float pbuf[64][65];
    __shared__ float rred[64][4];
    __shared__ float rsum[64];
    int tid = threadIdx.x;
    int z = blockIdx.x;
    int hh = (z >> 1) & 3;
    if (tid < 128) {
        float s = 0.f;
        for (int ch = 0; ch < NCHUNK; ++ch) s += partN[((size_t)z * NCHUNK + ch) * 128 + tid];
        float nv = fmaxf(sqrtf(s), 1e-12f);
        if (tid < 64) nqv[tid] = nv; else nkv[tid - 64] = nv;
    }
    __syncthreads();
    float tf = temp[hh];
    int d = tid >> 2, qq = tid & 3;
    float psum = 0.f;
    for (int e = qq * 16; e < qq * 16 + 16; ++e) {
        float s = 0.f;
        for (int ch = 0; ch < NCHUNK; ++ch) s += partS[((size_t)z * NCHUNK + ch) * 4096 + (size_t)d * 64 + e];
        float p = expf(tf * s / (nqv[d] * nkv[e]));
        pbuf[d][e] = p;
        psum += p;
    }
    rred[d][qq] = psum;
    __syncthreads();
    if (tid < 64) rsum[tid] = rred[tid][0] + rred[tid][1] + rred[tid][2] + rred[tid][3] + 1.0f;
    __syncthreads();
    for (int e = qq * 16; e < qq * 16 + 16; ++e)
        attnT[(size_t)z * 4096 + (size_t)e * 64 + d] = pbuf[d][e] / rsum[d];
}

// ---------- K7c: O = attn * V, written back to (c, sorted-position) layout ----------
__global__ __launch_bounds__(256) void k_attn_av(const float* __restrict__ attnT, const float* __restrict__ vs,
                                                 float* __restrict__ O1, float* __restrict__ O2) {
    __shared__ float at_s[4096];
    int tid = threadIdx.x;
    int z = blockIdx.y;
    int vi = z & 1, hh = (z >> 1) & 3, b = z >> 3;
    for (int l = 0; l < 16; ++l) at_s[l * 256 + tid] = attnT[(size_t)z * 4096 + l * 256 + tid];
    __syncthreads();
    int n = blockIdx.x * 256 + tid;
    float acc[64];
    #pragma unroll
    for (int d = 0; d < 64; ++d) acc[d] = 0.f;
    for (int e = 0; e < 64; ++e) {
        int cch = hh * 16 + (e >> 2), f = e & 3;
        size_t p = vi ? (size_t)(n * 4 + f) : (size_t)(f * NQ + n);
        float vv = vs[((size_t)(b * CC) + cch) * HW + p];
        const float* ar = &at_s[e * 64];
        #pragma unroll
        for (int d4 = 0; d4 < 16; ++d4) {
            float4 a4 = *(const float4*)&ar[d4 * 4];
            acc[d4 * 4 + 0] = fmaf(a4.x, vv, acc[d4 * 4 + 0]);
            acc[d4 * 4 + 1] = fmaf(a4.y, vv, acc[d4 * 4 + 1]);
            acc[d4 * 4 + 2] = fmaf(a4.z, vv, acc[d4 * 4 + 2]);
            acc[d4 * 4 + 3] = fmaf(a4.w, vv, acc[d4 * 4 + 3]);
        }
    }
    float* Ob = vi ? O2 : O1;
    #pragma unroll
    for (int d = 0; d < 64; ++d) {
        int cch = hh * 16 + (d >> 2), f = d & 3;
        size_t p = vi ? (size_t)(n * 4 + f) : (size_t)(f * NQ + n);
        Ob[((size_t)(b * CC) + cch) * HW + p] = acc[d];
    }
}

// ---------- K8: product in sorted domain, scatter to original positions via idxv ----------
__global__ void k_prod_scatter(const float* __restrict__ O1, const float* __restrict__ O2,
                               const int* __restrict__ idxv, float* __restrict__ pu) {
    int j = blockIdx.x * 256 + threadIdx.x;
    int row = blockIdx.y;
    size_t o = (size_t)row * HW + j;
    int p = idxv[o];
    pu[(size_t)row * HW + p] = O1[o] * O2[o];
}

// ---------- K9: proj GEMM 64x64 ----------
__global__ __launch_bounds__(256) void k_gemm_proj(const float* __restrict__ wp, const float* __restrict__ pu,
                                                   float* __restrict__ op) {
    __shared__ float wt[4096];  // wt[c*64+m] = wp[m*64+c]
    int tid = threadIdx.x;
    for (int l = 0; l < 16; ++l) {
        int i = l * 256 + tid;
        int m = i >> 6, c = i & 63;
        wt[c * 64 + m] = wp[i];
    }
    __syncthreads();
    int b = blockIdx.y;
    int n = blockIdx.x * 256 + tid;
    float acc[64];
    #pragma unroll
    for (int m = 0; m < 64; ++m) acc[m] = 0.f;
    const float* src = pu + (size_t)(b * CC) * HW + n;
    for (int c = 0; c < 64; ++c) {
        float xv = src[(size_t)c * HW];
        const float* wr = &wt[c * 64];
        #pragma unroll
        for (int m4 = 0; m4 < 16; ++m4) {
            float4 w4 = *(const float4*)&wr[m4 * 4];
            acc[m4 * 4 + 0] = fmaf(w4.x, xv, acc[m4 * 4 + 0]);
            acc[m4 * 4 + 1] = fmaf(w4.y, xv, acc[m4 * 4 + 1]);
            acc[m4 * 4 + 2] = fmaf(w4.z, xv, acc[m4 * 4 + 2]);
            acc[m4 * 4 + 3] = fmaf(w4.w, xv, acc[m4 * 4 + 3]);
        }
    }
    float* dst = op + (size_t)(b * CC) * HW + n;
    for (int m = 0; m < 64; ++m) dst[(size_t)m * HW] = acc[m];
}

// ---------- K10: spatial unsort scatter for c<32, copy c>=32 ----------
__global__ void k_final(const float* __restrict__ op, const int* __restrict__ idx_h,
                        const int* __restrict__ idx_w, float* __restrict__ out) {
    int i = blockIdx.x * 256 + threadIdx.x;
    int p = i % HW;
    int c = (i / HW) % CC;
    int b = i / (HW * CC);
    float v = op[i];
    if (c < CHF) {
        int h = p / IMW, w = p % IMW;
        size_t ib = ((size_t)(b * CHF) + c) * HW;
        int W0 = idx_w[ib + h * IMW + w];
        int H0 = idx_h[ib + h * IMW + W0];
        out[((size_t)(b * CC) + c) * HW + H0 * IMW + W0] = v;
    } else {
        out[i] = v;
    }
}

extern "C" void kernel_launch(void* const* d_in, const int* in_sizes, int n_in,
                              void* d_out, int out_size, void* d_ws, size_t ws_size,
                              hipStream_t stream) {
    (void)in_sizes; (void)n_in; (void)out_size; (void)ws_size;
    const float* x    = (const float*)d_in[0];
    const float* temp = (const float*)d_in[1];
    const float* wq   = (const float*)d_in[2];
    const float* wd3  = (const float*)d_in[3];
    const float* wd5  = (const float*)d_in[4];
    const float* wd7  = (const float*)d_in[5];
    const float* wf   = (const float*)d_in[6];
    const float* bf   = (const float*)d_in[7];
    const float* wp   = (const float*)d_in[8];
    float* out = (float*)d_out;
    float* ws = (float*)d_ws;

    // ---- workspace arena: peak 59,768,832 floats (~228 MiB) ----
    // Radix-phase liveness: idx_h, idx_w, idxv, cntG, keyA, keyB, vs, qkv(ALL of it —
    // q1/k1/q2/k2 planes are read later by gather4, so 36175872..59768832 is UNTOUCHABLE).
    int*      idx_h = (int*)(ws + 0);
    int*      idx_w = (int*)(ws + 2359296);
    float*    A     = ws + 4718592;
    float*    slice = ws + 4718592;                    // over dead A
    float*    q     = ws + 12582912;
    float*    qkv   = ws + 36175872;                   // ..59768832 — live until gather4 done
    int*      idxv  = (int*)(ws + 4718592);            // over dead slice: 4718592..9437184
    uint32_t* cntG  = (uint32_t*)(ws + 9437184);       // 128*12*2048 u32 = 3145728 — exact fit in hole 9437184..12582912
    uint64_t* keyA  = (uint64_t*)(ws + 12582912);      // over dead q: ..22020096
    uint64_t* keyB  = (uint64_t*)(ws + 22020096);      // ..31457280
    float*    vs    = ws + 31457280;                   // ..36175872
    float*    g4    = ws + 12582912;                   // over dead keyA+keyB (after radix)
    float*    O1    = ws + 36175872;                   // over dead qkv (after gather4/attn_qk)
    float*    O2    = ws + 40894464;
    float*    pu    = ws + 45613056;
    float*    op    = ws + 50331648;                   // written by k_gemm_proj
    float*    partS = ws + 55050240;                   // 2097152
    float*    partN = ws + 57147392;                   // 65536
    float*    attnT = ws + 57212928;                   // 65536 -> ends 57278464

    k_sort_h<<<12288, 128, 0, stream>>>(x, A, idx_h);
    k_sort_w<<<12288, 128, 0, stream>>>(A, idx_w);
    k_gemm_q<<<dim3(576, 5, 2), 256, 0, stream>>>(wq, A, x, q);

    for (int g = 0; g < 3; ++g) {
        for (int chunk = 0; chunk < 3; ++chunk) {
            int r0 = chunk * CROWS;
            if (g == 0)      k_dwconv<3><<<dim3(12, 320, 2), 256, 0, stream>>>(q, wd3, slice, r0);
            else if (g == 1) k_dwconv<5><<<dim3(12, 320, 2), 256, 0, stream>>>(q, wd5, slice, r0);
            else             k_dwconv<7><<<dim3(12, 320, 2), 256, 0, stream>>>(q, wd7, slice, r0);
            k_gemm_fuse<<<dim3(96, 5, 2), 256, 0, stream>>>(wf, slice, bf, qkv, g, r0);
        }
    }

    // 3 stable LSD passes of 11 bits over the value (bits 32..63).
    // Pass 0 reads qkv v-plane directly (build_keys fused); pass 2 writes vs+idxv (unpack fused).
    k_rcount<1><<<dim3(NSEG, 128), 256, 0, stream>>>(nullptr, qkv, cntG, 32);
    k_rscan<<<128, 256, 0, stream>>>(cntG);
    k_rscatter<1><<<dim3(NSEG, 128), 256, 0, stream>>>(nullptr, qkv, keyB, nullptr, nullptr, cntG, 32);
    k_rcount<0><<<dim3(NSEG, 128), 256, 0, stream>>>(keyB, nullptr, cntG, 43);
    k_rscan<<<128, 256, 0, stream>>>(cntG);
    k_rscatter<0><<<dim3(NSEG, 128), 256, 0, stream>>>(keyB, nullptr, keyA, nullptr, nullptr, cntG, 43);
    k_rcount<0><<<dim3(NSEG, 128), 256, 0, stream>>>(keyA, nullptr, cntG, 54);
    k_rscan<<<128, 256, 0, stream>>>(cntG);
    k_rscatter<2><<<dim3(NSEG, 128), 256, 0, stream>>>(keyA, nullptr, nullptr, vs, idxv, cntG, 54);

    k_gather4<<<256, 1024, 0, stream>>>(idxv, qkv, g4);

    k_attn_qk<<<dim3(NCHUNK, 16), 256, 0, stream>>>(g4, partS, partN);
    k_attn_softmax<<<16, 256, 0, stream>>>(partS, partN, temp, attnT);
    k_attn_av<<<dim3(36, 16), 256, 0, stream>>>(attnT, vs, O1, O2);

    k_prod_scatter<<<dim3(144, 128), 256, 0, stream>>>(O1, O2, idxv, pu);
    k_gemm_proj<<<dim3(144, 2), 256, 0, stream>>>(wp, pu, op);
    k_final<<<18432, 256, 0, stream>>>(op, idx_h, idx_w, out);
}